// Round 8
// baseline (1165.786 us; speedup 1.0000x reference)
//
#include <hip/hip_runtime.h>
#include <hip/hip_cooperative_groups.h>
#include <math.h>

namespace cg = cooperative_groups;

// Problem constants
static constexpr int B  = 2;
static constexpr int S  = 512;
static constexpr int D  = 256;
static constexpr int N  = 16;
static constexpr int DI = 512;
static constexpr int CHUNK = 32;
static constexpr int NCHUNK = S / CHUNK;   // 16
static constexpr int DN = DI * N;          // 8192

typedef unsigned int uint32;
typedef unsigned short ushort16;
using bf16x8 = __attribute__((ext_vector_type(8))) short;
using f32x4  = __attribute__((ext_vector_type(4))) float;

__device__ __forceinline__ ushort16 f2bf(float f) {
    uint32 u = __float_as_uint(f);
    u = (u + 0x7fffu + ((u >> 16) & 1u)) >> 16;   // RNE
    return (ushort16)u;
}
__device__ __forceinline__ float bflo(uint32 u) { return __uint_as_float(u << 16); }
__device__ __forceinline__ float bfhi(uint32 u) { return __uint_as_float(u & 0xffff0000u); }
__device__ __forceinline__ uint32 pk2(float a, float b) {
    return (uint32)(ushort16)f2bf(a) | ((uint32)(ushort16)f2bf(b) << 16);
}

// ---------------- LayerNorm: one wave per row, bf16 output ----------------
__global__ void ln_k(const float* __restrict__ x, const float* __restrict__ w,
                     const float* __restrict__ bias, ushort16* __restrict__ xnb) {
    int row = blockIdx.x;
    int lane = threadIdx.x;
    float4 v = *(const float4*)(x + row * D + lane * 4);
    float s = v.x + v.y + v.z + v.w;
    float q = v.x * v.x + v.y * v.y + v.z * v.z + v.w * v.w;
    for (int m = 1; m < 64; m <<= 1) { s += __shfl_xor(s, m); q += __shfl_xor(q, m); }
    float mu  = s * (1.0f / D);
    float var = q * (1.0f / D) - mu * mu;
    float rs  = rsqrtf(var + 1e-5f);
    float4 wv = *(const float4*)(w + lane * 4);
    float4 bv = *(const float4*)(bias + lane * 4);
    float4 o;
    o.x = (v.x - mu) * rs * wv.x + bv.x;
    o.y = (v.y - mu) * rs * wv.y + bv.y;
    o.z = (v.z - mu) * rs * wv.z + bv.z;
    o.w = (v.w - mu) * rs * wv.w + bv.w;
    uint2 pk;
    pk.x = pk2(o.x, o.y);
    pk.y = pk2(o.z, o.w);
    *(uint2*)(xnb + row * D + lane * 4) = pk;
}

// ---------------- generic f32 -> bf16 cast ----------------
__global__ void wcast_k(const float* __restrict__ src, ushort16* __restrict__ dst) {
    int i = blockIdx.x * 256 + threadIdx.x;
    float4 v = *(const float4*)(src + (size_t)i * 4);
    uint2 pk;
    pk.x = pk2(v.x, v.y);
    pk.y = pk2(v.z, v.w);
    *(uint2*)(dst + (size_t)i * 4) = pk;
}

// ---------------- bf16 MFMA GEMM: C[M,Nc] = A[M,K] @ W[Nc,K]^T (+res, f32 out) -------
__global__ __launch_bounds__(256) void gemmb_k(const ushort16* __restrict__ A,
                                               const ushort16* __restrict__ W,
                                               const float* __restrict__ res,
                                               float* __restrict__ C,
                                               int M, int Nc, int K) {
    __shared__ __align__(16) short As[64 * 40];
    __shared__ __align__(16) short Ws[64 * 40];
    int tid = threadIdx.x;
    int l = tid & 63, wid = tid >> 6;
    int wm = wid & 1, wn = wid >> 1;
    int row0 = blockIdx.y * 64, col0 = blockIdx.x * 64;
    int r = tid >> 2, kseg = (tid & 3) * 8;
    f32x4 acc[2][2] = {};
    for (int k0 = 0; k0 < K; k0 += 32) {
        *(uint4*)&As[r * 40 + kseg] = *(const uint4*)(A + (size_t)(row0 + r) * K + k0 + kseg);
        *(uint4*)&Ws[r * 40 + kseg] = *(const uint4*)(W + (size_t)(col0 + r) * K + k0 + kseg);
        __syncthreads();
        bf16x8 aF[2], bF[2];
        #pragma unroll
        for (int am = 0; am < 2; ++am)
            aF[am] = *(const bf16x8*)&As[(wm * 32 + am * 16 + (l & 15)) * 40 + (l >> 4) * 8];
        #pragma unroll
        for (int bn = 0; bn < 2; ++bn)
            bF[bn] = *(const bf16x8*)&Ws[(wn * 32 + bn * 16 + (l & 15)) * 40 + (l >> 4) * 8];
        #pragma unroll
        for (int am = 0; am < 2; ++am)
            #pragma unroll
            for (int bn = 0; bn < 2; ++bn)
                acc[am][bn] = __builtin_amdgcn_mfma_f32_16x16x32_bf16(aF[am], bF[bn], acc[am][bn], 0, 0, 0);
        __syncthreads();
    }
    #pragma unroll
    for (int am = 0; am < 2; ++am)
        #pragma unroll
        for (int bn = 0; bn < 2; ++bn) {
            int cc = col0 + wn * 32 + bn * 16 + (l & 15);
            #pragma unroll
            for (int reg = 0; reg < 4; ++reg) {
                int rr = row0 + wm * 32 + am * 16 + (l >> 4) * 4 + reg;
                float v = acc[am][bn][reg];
                if (res) v += res[(size_t)rr * Nc + cc];
                C[(size_t)rr * Nc + cc] = v;
            }
        }
}

// ---------------- cast xz[:, :DI] -> xpb (bf16, with 3-row zero halo per batch) -------
__global__ void cast_k(const float* __restrict__ xz, ushort16* __restrict__ xpb) {
    int i = blockIdx.x * 256 + threadIdx.x;
    int row = i >> 6;
    int off = (i & 63) * 8;
    int b = row >> 9, t = row & (S - 1);
    float4 v0 = *(const float4*)(xz + (size_t)row * (2 * DI) + off);
    float4 v1 = *(const float4*)(xz + (size_t)row * (2 * DI) + off + 4);
    uint4 pk;
    pk.x = pk2(v0.x, v0.y);
    pk.y = pk2(v0.z, v0.w);
    pk.z = pk2(v1.x, v1.y);
    pk.w = pk2(v1.z, v1.w);
    *(uint4*)(xpb + ((size_t)(b * (S + 3) + 3 + t)) * DI + off) = pk;
}

// ---------------- Causal conv via bf16 MFMA + bias + silu ----------------
__global__ __launch_bounds__(256) void convm_k(const ushort16* __restrict__ xpb,
                                               const float* __restrict__ conv_w,
                                               const float* __restrict__ conv_b,
                                               float* __restrict__ x_act) {
    __shared__ __align__(16) short AxS[35 * 40];
    __shared__ __align__(16) short WbS[4 * 32 * 40];
    int tid = threadIdx.x;
    int l = tid & 63, wid = tid >> 6;
    int wm = wid & 1, wn = wid >> 1;
    int o0 = blockIdx.x * 32;
    int mt = blockIdx.y;
    int b = mt >> 4, tl0 = (mt & 15) * 32;
    f32x4 acc = {0.f, 0.f, 0.f, 0.f};

    for (int k0 = 0; k0 < DI; k0 += 32) {
        if (tid < 140) {
            int rr = tid >> 2, seg = tid & 3;
            uint4 v = *(const uint4*)(xpb + ((size_t)(b * (S + 3) + tl0 + rr)) * DI + k0 + seg * 8);
            *(uint4*)&AxS[rr * 40 + seg * 8] = v;
        }
        #pragma unroll
        for (int it = 0; it < 4; ++it) {
            int p = it * 256 + tid;
            int o = p >> 5, i = p & 31;
            float4 w4 = *(const float4*)(conv_w + ((size_t)(o0 + o) * DI + (k0 + i)) * 4);
            WbS[(0 * 32 + o) * 40 + i] = (short)f2bf(w4.x);
            WbS[(1 * 32 + o) * 40 + i] = (short)f2bf(w4.y);
            WbS[(2 * 32 + o) * 40 + i] = (short)f2bf(w4.z);
            WbS[(3 * 32 + o) * 40 + i] = (short)f2bf(w4.w);
        }
        __syncthreads();
        #pragma unroll
        for (int k = 0; k < 4; ++k) {
            bf16x8 aF = *(const bf16x8*)&AxS[(wm * 16 + (l & 15) + k) * 40 + (l >> 4) * 8];
            bf16x8 bF = *(const bf16x8*)&WbS[(k * 32 + wn * 16 + (l & 15)) * 40 + (l >> 4) * 8];
            acc = __builtin_amdgcn_mfma_f32_16x16x32_bf16(aF, bF, acc, 0, 0, 0);
        }
        __syncthreads();
    }
    int oc = o0 + wn * 16 + (l & 15);
    float bia = conv_b[oc];
    #pragma unroll
    for (int reg = 0; reg < 4; ++reg) {
        int m = wm * 16 + (l >> 4) * 4 + reg;
        float v = acc[reg] + bia;
        x_act[((size_t)(b * S + tl0 + m)) * DI + oc] = v / (1.0f + __expf(-v));
    }
}

// ---------------- ssm = x_act @ W_xp^T (33 outputs) ----------------
__global__ void ssm_k(const float* __restrict__ x_act, const float* __restrict__ W_xp,
                      float* __restrict__ dt_raw, float* __restrict__ Bm, float* __restrict__ Cm) {
    int row = blockIdx.x * 4 + (threadIdx.x >> 6);
    int lane = threadIdx.x & 63;
    const float* xr = x_act + (size_t)row * DI + lane * 8;
    float4 v0 = *(const float4*)xr;
    float4 v1 = *(const float4*)(xr + 4);
    for (int j = 0; j < 2 * N + 1; ++j) {
        const float* wr = W_xp + (size_t)j * DI + lane * 8;
        float4 w0 = *(const float4*)wr;
        float4 w1 = *(const float4*)(wr + 4);
        float acc = v0.x * w0.x + v0.y * w0.y + v0.z * w0.z + v0.w * w0.w
                  + v1.x * w1.x + v1.y * w1.y + v1.z * w1.z + v1.w * w1.w;
        for (int m = 1; m < 64; m <<= 1) acc += __shfl_xor(acc, m);
        if (lane == 0) {
            if (j == 0)           dt_raw[row] = acc;
            else if (j < 1 + N)   Bm[(size_t)row * N + (j - 1)] = acc;
            else                  Cm[(size_t)row * N + (j - 1 - N)] = acc;
        }
    }
}

// ---------------- rdeg = 1/max(sum_{s<t} adj,1); flag[t] ----------------
__global__ void deg_k(const float* __restrict__ adj, float* __restrict__ rdeg, int* __restrict__ flagI) {
    int t = blockIdx.x & (S - 1), b = blockIdx.x >> 9;
    int lane = threadIdx.x;
    const float* row = adj + ((size_t)(b * S + t)) * S;
    float s = 0.0f; bool anyp = false;
    for (int i = lane; i < t; i += 64) { float v = row[i]; s += v; anyp |= (v > 0.0f); }
    for (int m = 1; m < 64; m <<= 1) s += __shfl_xor(s, m);
    bool any = __any(anyp);
    if (lane == 0) {
        rdeg[b * S + t] = 1.0f / fmaxf(s, 1.0f);
        if (t > 0 && any) atomicOr(flagI + t, 1);
    }
}

// ---------------- E = exp(-softplus(dt)), zs = silu(z) ----------------
__global__ void ez_k(const float* __restrict__ dt_raw, const float* __restrict__ W_dt,
                     const float* __restrict__ b_dt, const float* __restrict__ xz,
                     float* __restrict__ E, float* __restrict__ zs) {
    int i = blockIdx.x * 256 + threadIdx.x;
    int d = i & (DI - 1);
    int row = i >> 9;
    float vv = dt_raw[row] * W_dt[d] + b_dt[d];
    E[i] = 1.0f / (1.0f + __expf(vv));
    float z = xz[(size_t)row * (2 * DI) + DI + d];
    zs[i] = z / (1.0f + __expf(-z));
}

// ================= persistent cooperative scan kernel =================
// Grid: 192 blocks x 256 threads. Blocks [0,64): scan role (R5 structure);
// blocks [64,192): gpast role (Gold(c+1) via bf16 MFMA). grid.sync() per chunk.
// h, wr, br persist in registers across all 16 chunks.
__global__ __launch_bounds__(256) void scanall_k(const float* __restrict__ adj,
                                                 const float* __restrict__ x_act,
                                                 const float* __restrict__ E,
                                                 const float* __restrict__ Bm,
                                                 const float* __restrict__ Cm,
                                                 const float* __restrict__ rdeg,
                                                 const int* __restrict__ flagI,
                                                 const float* __restrict__ Wr,
                                                 const float* __restrict__ br,
                                                 ushort16* __restrict__ Gold,
                                                 ushort16* __restrict__ Gnew,
                                                 ushort16* __restrict__ histT,
                                                 const float* __restrict__ zs,
                                                 ushort16* __restrict__ yzb) {
    cg::grid_group grid = cg::this_grid();
    __shared__ __align__(16) char smemraw[16896];
    int tid = threadIdx.x;
    const size_t GBUF = (size_t)B * DN * 32;
    const bool isScan = blockIdx.x < 64;

    // persistent scan state
    float h = 0.0f;
    float wr[16];
    float brn = 0.0f;
    int b = 0, d0 = 0, n = 0, grp = 0, d = 0, dn = 0;
    if (isScan) {
        b = blockIdx.x >> 5;
        d0 = (blockIdx.x & 31) << 4;
        n = tid & 15; grp = tid >> 4;
        d = d0 + grp; dn = d * N + n;
        #pragma unroll
        for (int m = 0; m < 16; ++m) wr[m] = Wr[n * 16 + m];
        brn = br[n];
    }
    int gb = 0, gdn0 = 0;
    if (!isScan) {
        int idx = blockIdx.x - 64;
        gb = idx >> 6;
        gdn0 = (idx & 63) * 128;
    }

    #pragma unroll 1
    for (int c = 0; c < NCHUNK; ++c) {
        int cb = c * CHUNK;
        if (isScan) {
            float* adjblk = (float*)smemraw;             // [32][33]
            float* adjN   = (float*)(smemraw + 4224);    // [32][33]
            float* eL     = (float*)(smemraw + 8448);    // [32][16]
            float* xaL    = (float*)(smemraw + 10496);   // [32][16]
            float* BnL    = (float*)(smemraw + 12544);   // [32][16]
            float* CnL    = (float*)(smemraw + 14592);   // [32][16]
            float* rdegL  = (float*)(smemraw + 16640);   // [32]
            int*   flL    = (int*)  (smemraw + 16768);   // [32]

            // stage (all 256 threads, coalesced)
            {
                int j = tid >> 3;
                int s4 = (tid & 7) * 4;
                float4 av = *(const float4*)(adj + ((size_t)(b * S + cb + j)) * S + cb + s4);
                adjblk[j * 33 + s4 + 0] = av.x; adjblk[j * 33 + s4 + 1] = av.y;
                adjblk[j * 33 + s4 + 2] = av.z; adjblk[j * 33 + s4 + 3] = av.w;
                if (c < NCHUNK - 1) {
                    float4 aw = *(const float4*)(adj + ((size_t)(b * S + cb + CHUNK + j)) * S + cb + s4);
                    adjN[j * 33 + s4 + 0] = aw.x; adjN[j * 33 + s4 + 1] = aw.y;
                    adjN[j * 33 + s4 + 2] = aw.z; adjN[j * 33 + s4 + 3] = aw.w;
                }
                int ds2 = (tid & 7) * 2;
                float2 ev = *(const float2*)(E     + ((size_t)(b * S + cb + j)) * DI + d0 + ds2);
                float2 xv = *(const float2*)(x_act + ((size_t)(b * S + cb + j)) * DI + d0 + ds2);
                eL [j * 16 + ds2] = ev.x; eL [j * 16 + ds2 + 1] = ev.y;
                xaL[j * 16 + ds2] = xv.x; xaL[j * 16 + ds2 + 1] = xv.y;
                float2 bv = *(const float2*)(Bm + ((size_t)(b * S + cb + j)) * N + ds2);
                float2 cv = *(const float2*)(Cm + ((size_t)(b * S + cb + j)) * N + ds2);
                BnL[j * 16 + ds2] = bv.x; BnL[j * 16 + ds2 + 1] = bv.y;
                CnL[j * 16 + ds2] = cv.x; CnL[j * 16 + ds2 + 1] = cv.y;
                if (tid < 32) {
                    rdegL[tid] = rdeg[b * S + cb + tid];
                    flL[tid]   = flagI[cb + tid];
                }
            }

            // presum Gold + Gnew into registers (global, overlaps staging latency)
            float gsum[CHUNK];
            #pragma unroll
            for (int j = 0; j < CHUNK; ++j) gsum[j] = 0.0f;
            if (c >= 1) {
                const ushort16* gn = Gnew + (size_t)(c & 1) * GBUF + ((size_t)b * DN + dn) * 32;
                #pragma unroll
                for (int qi = 0; qi < 4; ++qi) {
                    uint4 q = *(const uint4*)(gn + qi * 8);
                    gsum[qi * 8 + 0] += bflo(q.x); gsum[qi * 8 + 1] += bfhi(q.x);
                    gsum[qi * 8 + 2] += bflo(q.y); gsum[qi * 8 + 3] += bfhi(q.y);
                    gsum[qi * 8 + 4] += bflo(q.z); gsum[qi * 8 + 5] += bfhi(q.z);
                    gsum[qi * 8 + 6] += bflo(q.w); gsum[qi * 8 + 7] += bfhi(q.w);
                }
            }
            if (c >= 2) {
                const ushort16* go = Gold + (size_t)(c & 1) * GBUF + ((size_t)b * DN + dn) * 32;
                #pragma unroll
                for (int qi = 0; qi < 4; ++qi) {
                    uint4 q = *(const uint4*)(go + qi * 8);
                    gsum[qi * 8 + 0] += bflo(q.x); gsum[qi * 8 + 1] += bfhi(q.x);
                    gsum[qi * 8 + 2] += bflo(q.y); gsum[qi * 8 + 3] += bfhi(q.y);
                    gsum[qi * 8 + 4] += bflo(q.z); gsum[qi * 8 + 5] += bfhi(q.z);
                    gsum[qi * 8 + 6] += bflo(q.w); gsum[qi * 8 + 7] += bfhi(q.w);
                }
            }
            __syncthreads();

            float hreg[CHUNK];
            #pragma unroll
            for (int j = 0; j < CHUNK; ++j) {
                float e  = eL [j * 16 + grp];
                float xa = xaL[j * 16 + grp];
                float Bn = BnL[j * 16 + n];
                h = h * e + xa * Bn;

                // triangle: all but the last term (they depend on hreg[<=j-2], ready early)
                float g0 = gsum[j], g1 = 0.0f, g2 = 0.0f, g3 = 0.0f;
                const float* ar = adjblk + j * 33;
                #pragma unroll
                for (int sp = 0; sp < j - 1; ++sp) {
                    float a = ar[sp];
                    if ((sp & 3) == 0) g0 += a * hreg[sp];
                    else if ((sp & 3) == 1) g1 += a * hreg[sp];
                    else if ((sp & 3) == 2) g2 += a * hreg[sp];
                    else g3 += a * hreg[sp];
                }
                float gr = (g0 + g1) + (g2 + g3);
                if (j > 0) gr += ar[j - 1] * hreg[j - 1];   // 1 FMA from h_{j-1}

                // Wr-mix on unscaled gr; fold rdeg after
                float m0 = 0.0f, m1 = 0.0f, m2 = 0.0f, m3 = 0.0f;
                #pragma unroll
                for (int p = 0; p < 4; ++p) {
                    m0 += __shfl(gr, p * 4 + 0, 16) * wr[p * 4 + 0];
                    m1 += __shfl(gr, p * 4 + 1, 16) * wr[p * 4 + 1];
                    m2 += __shfl(gr, p * 4 + 2, 16) * wr[p * 4 + 2];
                    m3 += __shfl(gr, p * 4 + 3, 16) * wr[p * 4 + 3];
                }
                float acc = fmaf(rdegL[j], (m0 + m1) + (m2 + m3), brn);
                if (flL[j]) h += 0.1f * acc / (1.0f + __expf(-acc));
                hreg[j] = h;
            }

            // tail: histT (s-contiguous), y outputs, Gnew(c+1)
            {
                ushort16* ht = histT + ((size_t)b * DN + dn) * S + cb;
                #pragma unroll
                for (int qi = 0; qi < 4; ++qi) {
                    uint4 q;
                    q.x = pk2(hreg[qi * 8 + 0], hreg[qi * 8 + 1]);
                    q.y = pk2(hreg[qi * 8 + 2], hreg[qi * 8 + 3]);
                    q.z = pk2(hreg[qi * 8 + 4], hreg[qi * 8 + 5]);
                    q.w = pk2(hreg[qi * 8 + 6], hreg[qi * 8 + 7]);
                    *(uint4*)(ht + qi * 8) = q;
                }
            }
            size_t baseTD = ((size_t)(b * S + cb)) * DI + d;
            #pragma unroll
            for (int j = 0; j < CHUNK; ++j) {
                float rs = hreg[j] * CnL[j * 16 + n];
                rs += __shfl_xor(rs, 1);
                rs += __shfl_xor(rs, 2);
                rs += __shfl_xor(rs, 4);
                rs += __shfl_xor(rs, 8);
                if (n == 0) {
                    float zv = zs[baseTD + (size_t)j * DI];
                    yzb[baseTD + (size_t)j * DI] = f2bf(rs * zv);
                }
            }
            if (c < NCHUNK - 1) {
                float gn[CHUNK];
                #pragma unroll
                for (int jj = 0; jj < CHUNK; ++jj) {
                    float a0 = 0.0f, a1 = 0.0f;
                    const float* arN = adjN + jj * 33;
                    #pragma unroll
                    for (int sp = 0; sp < CHUNK; sp += 2) {
                        a0 += arN[sp]     * hreg[sp];
                        a1 += arN[sp + 1] * hreg[sp + 1];
                    }
                    gn[jj] = a0 + a1;
                }
                ushort16* gw = Gnew + (size_t)((c + 1) & 1) * GBUF + ((size_t)b * DN + dn) * 32;
                #pragma unroll
                for (int qi = 0; qi < 4; ++qi) {
                    uint4 q;
                    q.x = pk2(gn[qi * 8 + 0], gn[qi * 8 + 1]);
                    q.y = pk2(gn[qi * 8 + 2], gn[qi * 8 + 3]);
                    q.z = pk2(gn[qi * 8 + 4], gn[qi * 8 + 5]);
                    q.w = pk2(gn[qi * 8 + 6], gn[qi * 8 + 7]);
                    *(uint4*)(gw + qi * 8) = q;
                }
            }
        } else if (c >= 1 && c < NCHUNK - 1) {
            // ---------------- gpast role: Gold(c+1) via bf16 MFMA ----------------
            short* As = (short*)smemraw;            // [32][40]
            short* Ws = (short*)(smemraw + 2560);   // [128][40]
            int l = tid & 63, wid = tid >> 6;
            int wjm = wid & 1;
            int wn2 = wid >> 1;

            f32x4 acc[4] = {};
            for (int ks = 0; ks < c; ++ks) {
                {
                    int j = tid >> 3, s4 = (tid & 7) * 4;
                    float4 av = *(const float4*)(adj + ((size_t)(gb * S + cb + CHUNK + j)) * S + ks * CHUNK + s4);
                    As[j * 40 + s4 + 0] = (short)f2bf(av.x);
                    As[j * 40 + s4 + 1] = (short)f2bf(av.y);
                    As[j * 40 + s4 + 2] = (short)f2bf(av.z);
                    As[j * 40 + s4 + 3] = (short)f2bf(av.w);
                    #pragma unroll
                    for (int q = 0; q < 2; ++q) {
                        int e = q * 256 + tid;
                        int r = e >> 2, seg = e & 3;
                        *(uint4*)&Ws[r * 40 + seg * 8] =
                            *(const uint4*)(histT + ((size_t)gb * DN + gdn0 + r) * S + ks * CHUNK + seg * 8);
                    }
                }
                __syncthreads();
                bf16x8 aF = *(const bf16x8*)&As[(wjm * 16 + (l & 15)) * 40 + (l >> 4) * 8];
                #pragma unroll
                for (int bn = 0; bn < 4; ++bn) {
                    bf16x8 bF = *(const bf16x8*)&Ws[(wn2 * 64 + bn * 16 + (l & 15)) * 40 + (l >> 4) * 8];
                    acc[bn] = __builtin_amdgcn_mfma_f32_16x16x32_bf16(aF, bF, acc[bn], 0, 0, 0);
                }
                __syncthreads();
            }
            int jb = wjm * 16 + (l >> 4) * 4;
            ushort16* gbase = Gold + (size_t)((c + 1) & 1) * GBUF;
            #pragma unroll
            for (int bn = 0; bn < 4; ++bn) {
                int dnc = gdn0 + wn2 * 64 + bn * 16 + (l & 15);
                uint2 o;
                o.x = pk2(acc[bn][0], acc[bn][1]);
                o.y = pk2(acc[bn][2], acc[bn][3]);
                *(uint2*)(gbase + ((size_t)gb * DN + dnc) * 32 + jb) = o;
            }
        }
        __threadfence();
        grid.sync();
    }
}

// ---------------- launch ----------------
extern "C" void kernel_launch(void* const* d_in, const int* in_sizes, int n_in,
                              void* d_out, int out_size, void* d_ws, size_t ws_size,
                              hipStream_t stream) {
    const float* x      = (const float*)d_in[0];
    const float* adj    = (const float*)d_in[1];
    const float* ln_w   = (const float*)d_in[2];
    const float* ln_b   = (const float*)d_in[3];
    const float* W_in   = (const float*)d_in[4];
    const float* conv_w = (const float*)d_in[5];
    const float* conv_b = (const float*)d_in[6];
    const float* W_xp   = (const float*)d_in[7];
    const float* W_dt   = (const float*)d_in[8];
    const float* b_dt   = (const float*)d_in[9];
    const float* Wr     = (const float*)d_in[10];
    const float* br     = (const float*)d_in[11];
    const float* W_out  = (const float*)d_in[12];
    float* out = (float*)d_out;

    float* ws = (float*)d_ws;
    size_t off = 0;
    float* xz     = ws + off; off += (size_t)B * S * 2 * DI;
    float* x_act  = ws + off; off += (size_t)B * S * DI;
    float* dt_raw = ws + off; off += (size_t)B * S;
    float* Bmb    = ws + off; off += (size_t)B * S * N;
    float* Cmb    = ws + off; off += (size_t)B * S * N;
    float* rdegp  = ws + off; off += (size_t)B * S;
    int*   flagI  = (int*)(ws + off); off += S;
    float* Ebuf   = ws + off; off += (size_t)B * S * DI;
    float* zsbuf  = ws + off; off += (size_t)B * S * DI;
    ushort16* xnb    = (ushort16*)(ws + off); off += (size_t)B * S * D / 2;
    ushort16* yzb    = (ushort16*)(ws + off); off += (size_t)B * S * DI / 2;
    ushort16* histT  = (ushort16*)(ws + off); off += (size_t)B * DN * S / 2;
    ushort16* Gold   = (ushort16*)(ws + off); off += (size_t)2 * B * DN * 32 / 2;
    ushort16* Gnew   = (ushort16*)(ws + off); off += (size_t)2 * B * DN * 32 / 2;
    ushort16* xpb    = (ushort16*)(ws + off); off += (size_t)B * (S + 3) * DI / 2;
    ushort16* W_inb  = (ushort16*)(ws + off); off += (size_t)2 * DI * D / 2;
    ushort16* W_outb = (ushort16*)(ws + off); off += (size_t)D * DI / 2;

    hipMemsetAsync(flagI, 0, S * sizeof(int), stream);
    hipMemsetAsync(xpb, 0, (size_t)B * (S + 3) * DI * 2, stream);

    ln_k<<<B * S, 64, 0, stream>>>(x, ln_w, ln_b, xnb);
    wcast_k<<<(2 * DI * D) / 1024, 256, 0, stream>>>(W_in, W_inb);
    wcast_k<<<(D * DI) / 1024, 256, 0, stream>>>(W_out, W_outb);
    gemmb_k<<<dim3(2 * DI / 64, B * S / 64), 256, 0, stream>>>(xnb, W_inb, nullptr, xz, B * S, 2 * DI, D);
    cast_k<<<B * S * DI / (256 * 8), 256, 0, stream>>>(xz, xpb);
    convm_k<<<dim3(DI / 32, B * S / 32), 256, 0, stream>>>(xpb, conv_w, conv_b, x_act);
    ssm_k<<<B * S / 4, 256, 0, stream>>>(x_act, W_xp, dt_raw, Bmb, Cmb);
    deg_k<<<B * S, 64, 0, stream>>>(adj, rdegp, flagI);
    ez_k<<<B * S * DI / 256, 256, 0, stream>>>(dt_raw, W_dt, b_dt, xz, Ebuf, zsbuf);

    {
        void* args[] = { (void*)&adj, (void*)&x_act, (void*)&Ebuf, (void*)&Bmb,
                         (void*)&Cmb, (void*)&rdegp, (void*)&flagI, (void*)&Wr,
                         (void*)&br, (void*)&Gold, (void*)&Gnew, (void*)&histT,
                         (void*)&zsbuf, (void*)&yzb };
        hipLaunchCooperativeKernel((const void*)scanall_k, dim3(192), dim3(256),
                                   args, 0, stream);
    }

    gemmb_k<<<dim3(D / 64, B * S / 64), 256, 0, stream>>>(yzb, W_outb, x, out, B * S, D, DI);
}

// Round 9
// 490.903 us; speedup vs baseline: 2.3748x; 2.3748x over previous
//
#include <hip/hip_runtime.h>
#include <math.h>

// Problem constants
static constexpr int B  = 2;
static constexpr int S  = 512;
static constexpr int D  = 256;
static constexpr int N  = 16;
static constexpr int DI = 512;
static constexpr int CHUNK = 32;
static constexpr int NCHUNK = S / CHUNK;   // 16
static constexpr int DN = DI * N;          // 8192

typedef unsigned int uint32;
typedef unsigned short ushort16;
using bf16x8 = __attribute__((ext_vector_type(8))) short;
using f32x4  = __attribute__((ext_vector_type(4))) float;

__device__ __forceinline__ ushort16 f2bf(float f) {
    uint32 u = __float_as_uint(f);
    u = (u + 0x7fffu + ((u >> 16) & 1u)) >> 16;   // RNE
    return (ushort16)u;
}
__device__ __forceinline__ float bflo(uint32 u) { return __uint_as_float(u << 16); }
__device__ __forceinline__ float bfhi(uint32 u) { return __uint_as_float(u & 0xffff0000u); }
__device__ __forceinline__ uint32 pk2(float a, float b) {
    return (uint32)(ushort16)f2bf(a) | ((uint32)(ushort16)f2bf(b) << 16);
}

// ---------------- LayerNorm: one wave per row, bf16 output ----------------
__global__ void ln_k(const float* __restrict__ x, const float* __restrict__ w,
                     const float* __restrict__ bias, ushort16* __restrict__ xnb) {
    int row = blockIdx.x;
    int lane = threadIdx.x;
    float4 v = *(const float4*)(x + row * D + lane * 4);
    float s = v.x + v.y + v.z + v.w;
    float q = v.x * v.x + v.y * v.y + v.z * v.z + v.w * v.w;
    for (int m = 1; m < 64; m <<= 1) { s += __shfl_xor(s, m); q += __shfl_xor(q, m); }
    float mu  = s * (1.0f / D);
    float var = q * (1.0f / D) - mu * mu;
    float rs  = rsqrtf(var + 1e-5f);
    float4 wv = *(const float4*)(w + lane * 4);
    float4 bv = *(const float4*)(bias + lane * 4);
    float4 o;
    o.x = (v.x - mu) * rs * wv.x + bv.x;
    o.y = (v.y - mu) * rs * wv.y + bv.y;
    o.z = (v.z - mu) * rs * wv.z + bv.z;
    o.w = (v.w - mu) * rs * wv.w + bv.w;
    uint2 pk;
    pk.x = pk2(o.x, o.y);
    pk.y = pk2(o.z, o.w);
    *(uint2*)(xnb + row * D + lane * 4) = pk;
}

// ---------------- generic f32 -> bf16 cast ----------------
__global__ void wcast_k(const float* __restrict__ src, ushort16* __restrict__ dst) {
    int i = blockIdx.x * 256 + threadIdx.x;
    float4 v = *(const float4*)(src + (size_t)i * 4);
    uint2 pk;
    pk.x = pk2(v.x, v.y);
    pk.y = pk2(v.z, v.w);
    *(uint2*)(dst + (size_t)i * 4) = pk;
}

// ---------------- bf16 MFMA GEMM: C[M,Nc] = A[M,K] @ W[Nc,K]^T (+res, f32 out) -------
__global__ __launch_bounds__(256) void gemmb_k(const ushort16* __restrict__ A,
                                               const ushort16* __restrict__ W,
                                               const float* __restrict__ res,
                                               float* __restrict__ C,
                                               int M, int Nc, int K) {
    __shared__ __align__(16) short As[64 * 40];
    __shared__ __align__(16) short Ws[64 * 40];
    int tid = threadIdx.x;
    int l = tid & 63, wid = tid >> 6;
    int wm = wid & 1, wn = wid >> 1;
    int row0 = blockIdx.y * 64, col0 = blockIdx.x * 64;
    int r = tid >> 2, kseg = (tid & 3) * 8;
    f32x4 acc[2][2] = {};
    for (int k0 = 0; k0 < K; k0 += 32) {
        *(uint4*)&As[r * 40 + kseg] = *(const uint4*)(A + (size_t)(row0 + r) * K + k0 + kseg);
        *(uint4*)&Ws[r * 40 + kseg] = *(const uint4*)(W + (size_t)(col0 + r) * K + k0 + kseg);
        __syncthreads();
        bf16x8 aF[2], bF[2];
        #pragma unroll
        for (int am = 0; am < 2; ++am)
            aF[am] = *(const bf16x8*)&As[(wm * 32 + am * 16 + (l & 15)) * 40 + (l >> 4) * 8];
        #pragma unroll
        for (int bn = 0; bn < 2; ++bn)
            bF[bn] = *(const bf16x8*)&Ws[(wn * 32 + bn * 16 + (l & 15)) * 40 + (l >> 4) * 8];
        #pragma unroll
        for (int am = 0; am < 2; ++am)
            #pragma unroll
            for (int bn = 0; bn < 2; ++bn)
                acc[am][bn] = __builtin_amdgcn_mfma_f32_16x16x32_bf16(aF[am], bF[bn], acc[am][bn], 0, 0, 0);
        __syncthreads();
    }
    #pragma unroll
    for (int am = 0; am < 2; ++am)
        #pragma unroll
        for (int bn = 0; bn < 2; ++bn) {
            int cc = col0 + wn * 32 + bn * 16 + (l & 15);
            #pragma unroll
            for (int reg = 0; reg < 4; ++reg) {
                int rr = row0 + wm * 32 + am * 16 + (l >> 4) * 4 + reg;
                float v = acc[am][bn][reg];
                if (res) v += res[(size_t)rr * Nc + cc];
                C[(size_t)rr * Nc + cc] = v;
            }
        }
}

// ---------------- cast xz[:, :DI] -> xpb (bf16, with 3-row zero halo per batch) -------
__global__ void cast_k(const float* __restrict__ xz, ushort16* __restrict__ xpb) {
    int i = blockIdx.x * 256 + threadIdx.x;
    int row = i >> 6;
    int off = (i & 63) * 8;
    int b = row >> 9, t = row & (S - 1);
    float4 v0 = *(const float4*)(xz + (size_t)row * (2 * DI) + off);
    float4 v1 = *(const float4*)(xz + (size_t)row * (2 * DI) + off + 4);
    uint4 pk;
    pk.x = pk2(v0.x, v0.y);
    pk.y = pk2(v0.z, v0.w);
    pk.z = pk2(v1.x, v1.y);
    pk.w = pk2(v1.z, v1.w);
    *(uint4*)(xpb + ((size_t)(b * (S + 3) + 3 + t)) * DI + off) = pk;
}

// ---------------- Causal conv via bf16 MFMA + bias + silu ----------------
__global__ __launch_bounds__(256) void convm_k(const ushort16* __restrict__ xpb,
                                               const float* __restrict__ conv_w,
                                               const float* __restrict__ conv_b,
                                               float* __restrict__ x_act) {
    __shared__ __align__(16) short AxS[35 * 40];
    __shared__ __align__(16) short WbS[4 * 32 * 40];
    int tid = threadIdx.x;
    int l = tid & 63, wid = tid >> 6;
    int wm = wid & 1, wn = wid >> 1;
    int o0 = blockIdx.x * 32;
    int mt = blockIdx.y;
    int b = mt >> 4, tl0 = (mt & 15) * 32;
    f32x4 acc = {0.f, 0.f, 0.f, 0.f};

    for (int k0 = 0; k0 < DI; k0 += 32) {
        if (tid < 140) {
            int rr = tid >> 2, seg = tid & 3;
            uint4 v = *(const uint4*)(xpb + ((size_t)(b * (S + 3) + tl0 + rr)) * DI + k0 + seg * 8);
            *(uint4*)&AxS[rr * 40 + seg * 8] = v;
        }
        #pragma unroll
        for (int it = 0; it < 4; ++it) {
            int p = it * 256 + tid;
            int o = p >> 5, i = p & 31;
            float4 w4 = *(const float4*)(conv_w + ((size_t)(o0 + o) * DI + (k0 + i)) * 4);
            WbS[(0 * 32 + o) * 40 + i] = (short)f2bf(w4.x);
            WbS[(1 * 32 + o) * 40 + i] = (short)f2bf(w4.y);
            WbS[(2 * 32 + o) * 40 + i] = (short)f2bf(w4.z);
            WbS[(3 * 32 + o) * 40 + i] = (short)f2bf(w4.w);
        }
        __syncthreads();
        #pragma unroll
        for (int k = 0; k < 4; ++k) {
            bf16x8 aF = *(const bf16x8*)&AxS[(wm * 16 + (l & 15) + k) * 40 + (l >> 4) * 8];
            bf16x8 bF = *(const bf16x8*)&WbS[(k * 32 + wn * 16 + (l & 15)) * 40 + (l >> 4) * 8];
            acc = __builtin_amdgcn_mfma_f32_16x16x32_bf16(aF, bF, acc, 0, 0, 0);
        }
        __syncthreads();
    }
    int oc = o0 + wn * 16 + (l & 15);
    float bia = conv_b[oc];
    #pragma unroll
    for (int reg = 0; reg < 4; ++reg) {
        int m = wm * 16 + (l >> 4) * 4 + reg;
        float v = acc[reg] + bia;
        x_act[((size_t)(b * S + tl0 + m)) * DI + oc] = v / (1.0f + __expf(-v));
    }
}

// ---------------- ssm = x_act @ W_xp^T (33 outputs) ----------------
__global__ void ssm_k(const float* __restrict__ x_act, const float* __restrict__ W_xp,
                      float* __restrict__ dt_raw, float* __restrict__ Bm, float* __restrict__ Cm) {
    int row = blockIdx.x * 4 + (threadIdx.x >> 6);
    int lane = threadIdx.x & 63;
    const float* xr = x_act + (size_t)row * DI + lane * 8;
    float4 v0 = *(const float4*)xr;
    float4 v1 = *(const float4*)(xr + 4);
    for (int j = 0; j < 2 * N + 1; ++j) {
        const float* wr = W_xp + (size_t)j * DI + lane * 8;
        float4 w0 = *(const float4*)wr;
        float4 w1 = *(const float4*)(wr + 4);
        float acc = v0.x * w0.x + v0.y * w0.y + v0.z * w0.z + v0.w * w0.w
                  + v1.x * w1.x + v1.y * w1.y + v1.z * w1.z + v1.w * w1.w;
        for (int m = 1; m < 64; m <<= 1) acc += __shfl_xor(acc, m);
        if (lane == 0) {
            if (j == 0)           dt_raw[row] = acc;
            else if (j < 1 + N)   Bm[(size_t)row * N + (j - 1)] = acc;
            else                  Cm[(size_t)row * N + (j - 1 - N)] = acc;
        }
    }
}

// ---------------- rdeg = 1/max(sum_{s<t} adj,1); flag[t] ----------------
__global__ void deg_k(const float* __restrict__ adj, float* __restrict__ rdeg, int* __restrict__ flagI) {
    int t = blockIdx.x & (S - 1), b = blockIdx.x >> 9;
    int lane = threadIdx.x;
    const float* row = adj + ((size_t)(b * S + t)) * S;
    float s = 0.0f; bool anyp = false;
    for (int i = lane; i < t; i += 64) { float v = row[i]; s += v; anyp |= (v > 0.0f); }
    for (int m = 1; m < 64; m <<= 1) s += __shfl_xor(s, m);
    bool any = __any(anyp);
    if (lane == 0) {
        rdeg[b * S + t] = 1.0f / fmaxf(s, 1.0f);
        if (t > 0 && any) atomicOr(flagI + t, 1);
    }
}

// ---------------- E = exp(-softplus(dt)), zs = silu(z) ----------------
__global__ void ez_k(const float* __restrict__ dt_raw, const float* __restrict__ W_dt,
                     const float* __restrict__ b_dt, const float* __restrict__ xz,
                     float* __restrict__ E, float* __restrict__ zs) {
    int i = blockIdx.x * 256 + threadIdx.x;
    int d = i & (DI - 1);
    int row = i >> 9;
    float vv = dt_raw[row] * W_dt[d] + b_dt[d];
    E[i] = 1.0f / (1.0f + __expf(vv));
    float z = xz[(size_t)row * (2 * DI) + DI + d];
    zs[i] = z / (1.0f + __expf(-z));
}

// ================= fused chunk kernel (128-thread blocks, 256 blocks) =================
// histT: bf16 [b][dn][s]; Gold/Gnew: bf16 [parity][b][dn][j32]
// blocks [0,128):   scan role: 8 d-groups x 16 n = 128 lanes (2 waves/CU).
//                   G_new computed via MFMA from LDS-transposed hreg.
// blocks [128,256): gpast role: MFMA Gold(c+1) over chunks 0..c-1, 128 dn/block.
__global__ __launch_bounds__(128) void chunk_k(const float* __restrict__ adj,
                                               const float* __restrict__ x_act,
                                               const float* __restrict__ E,
                                               const float* __restrict__ Bm,
                                               const float* __restrict__ Cm,
                                               const float* __restrict__ rdeg,
                                               const int* __restrict__ flagI,
                                               const float* __restrict__ Wr,
                                               const float* __restrict__ br,
                                               ushort16* __restrict__ Gold,
                                               ushort16* __restrict__ Gnew,
                                               ushort16* __restrict__ histT,
                                               float* __restrict__ hlast,
                                               const float* __restrict__ zs,
                                               ushort16* __restrict__ yzb, int c) {
    int tid = threadIdx.x;
    int cb = c * CHUNK;
    const size_t GBUF = (size_t)B * DN * 32;   // ushorts per parity

    if (blockIdx.x < 128) {
        // ---------------- scan role ----------------
        __shared__ float adjblk[32 * 36];           // f32 triangle, stride 36
        __shared__ float eL[32 * 8];
        __shared__ float xaL[32 * 8];
        __shared__ float BnL[32 * 16];
        __shared__ float CnL[32 * 16];
        __shared__ float rdegL[32];
        __shared__ int   flL[32];
        __shared__ float gx[128];
        __shared__ __align__(16) short hT[4 * 128 * 8];   // seg-major [kseg][dn][8sp]
        __shared__ __align__(16) short AsN[32 * 40];      // adjN bf16, stride 40

        int b = blockIdx.x >> 6;
        int d0 = (blockIdx.x & 63) << 3;
        int n = tid & 15, grp = tid >> 4;          // grp 0..7
        int d = d0 + grp;
        int dn = d * N + n;

        // stage (coalesced)
        {
            int j = tid >> 2;
            int s8 = (tid & 3) * 8;
            const float* arow = adj + ((size_t)(b * S + cb + j)) * S + cb + s8;
            float4 a0 = *(const float4*)arow;
            float4 a1 = *(const float4*)(arow + 4);
            float* dstp = adjblk + j * 36 + s8;
            dstp[0] = a0.x; dstp[1] = a0.y; dstp[2] = a0.z; dstp[3] = a0.w;
            dstp[4] = a1.x; dstp[5] = a1.y; dstp[6] = a1.z; dstp[7] = a1.w;
            int dd = (tid & 3) * 2;
            float2 ev = *(const float2*)(E     + ((size_t)(b * S + cb + j)) * DI + d0 + dd);
            float2 xv = *(const float2*)(x_act + ((size_t)(b * S + cb + j)) * DI + d0 + dd);
            eL [j * 8 + dd] = ev.x; eL [j * 8 + dd + 1] = ev.y;
            xaL[j * 8 + dd] = xv.x; xaL[j * 8 + dd + 1] = xv.y;
            int nn = (tid & 3) * 4;
            float4 bv = *(const float4*)(Bm + ((size_t)(b * S + cb + j)) * N + nn);
            float4 cv = *(const float4*)(Cm + ((size_t)(b * S + cb + j)) * N + nn);
            BnL[j * 16 + nn] = bv.x; BnL[j * 16 + nn + 1] = bv.y;
            BnL[j * 16 + nn + 2] = bv.z; BnL[j * 16 + nn + 3] = bv.w;
            CnL[j * 16 + nn] = cv.x; CnL[j * 16 + nn + 1] = cv.y;
            CnL[j * 16 + nn + 2] = cv.z; CnL[j * 16 + nn + 3] = cv.w;
            if (tid < 32) {
                rdegL[tid] = rdeg[b * S + cb + tid];
                flL[tid]   = flagI[cb + tid];
            }
        }

        // presum Gold + Gnew into registers
        float gsum[CHUNK];
        #pragma unroll
        for (int j = 0; j < CHUNK; ++j) gsum[j] = 0.0f;
        if (c >= 1) {
            const ushort16* gn = Gnew + (size_t)(c & 1) * GBUF + ((size_t)b * DN + dn) * 32;
            #pragma unroll
            for (int qi = 0; qi < 4; ++qi) {
                uint4 q = *(const uint4*)(gn + qi * 8);
                gsum[qi * 8 + 0] += bflo(q.x); gsum[qi * 8 + 1] += bfhi(q.x);
                gsum[qi * 8 + 2] += bflo(q.y); gsum[qi * 8 + 3] += bfhi(q.y);
                gsum[qi * 8 + 4] += bflo(q.z); gsum[qi * 8 + 5] += bfhi(q.z);
                gsum[qi * 8 + 6] += bflo(q.w); gsum[qi * 8 + 7] += bfhi(q.w);
            }
        }
        if (c >= 2) {
            const ushort16* go = Gold + (size_t)(c & 1) * GBUF + ((size_t)b * DN + dn) * 32;
            #pragma unroll
            for (int qi = 0; qi < 4; ++qi) {
                uint4 q = *(const uint4*)(go + qi * 8);
                gsum[qi * 8 + 0] += bflo(q.x); gsum[qi * 8 + 1] += bfhi(q.x);
                gsum[qi * 8 + 2] += bflo(q.y); gsum[qi * 8 + 3] += bfhi(q.y);
                gsum[qi * 8 + 4] += bflo(q.z); gsum[qi * 8 + 5] += bfhi(q.z);
                gsum[qi * 8 + 6] += bflo(q.w); gsum[qi * 8 + 7] += bfhi(q.w);
            }
        }

        float wr[16];
        #pragma unroll
        for (int m = 0; m < 16; ++m) wr[m] = Wr[n * 16 + m];
        float brn = br[n];
        float h = (c == 0) ? 0.0f : hlast[b * DN + dn];
        __syncthreads();

        float hreg[CHUNK];
        #pragma unroll
        for (int j = 0; j < CHUNK; ++j) {
            float e  = eL [j * 8 + grp];
            float xa = xaL[j * 8 + grp];
            float Bn = BnL[j * 16 + n];
            h = h * e + xa * Bn;

            // triangle via float4 broadcast reads
            float g0 = gsum[j], g1 = 0.0f, g2 = 0.0f, g3 = 0.0f;
            const float* ar = adjblk + j * 36;
            int sp = 0;
            #pragma unroll
            for (; sp + 4 <= j; sp += 4) {
                float4 av = *(const float4*)(ar + sp);
                g0 += av.x * hreg[sp];     g1 += av.y * hreg[sp + 1];
                g2 += av.z * hreg[sp + 2]; g3 += av.w * hreg[sp + 3];
            }
            #pragma unroll
            for (; sp < j; ++sp) g0 += ar[sp] * hreg[sp];
            float gr = (g0 + g1) + (g2 + g3);

            // Wr-mix via LDS round-trip (write g, fence, read group row)
            gx[tid] = gr;
            __threadfence_block();
            float4 gA = *(const float4*)&gx[grp * 16];
            float4 gB = *(const float4*)&gx[grp * 16 + 4];
            float4 gC = *(const float4*)&gx[grp * 16 + 8];
            float4 gD = *(const float4*)&gx[grp * 16 + 12];
            float m0 = gA.x * wr[0]  + gA.y * wr[1]  + gA.z * wr[2]  + gA.w * wr[3];
            float m1 = gB.x * wr[4]  + gB.y * wr[5]  + gB.z * wr[6]  + gB.w * wr[7];
            float m2 = gC.x * wr[8]  + gC.y * wr[9]  + gC.z * wr[10] + gC.w * wr[11];
            float m3 = gD.x * wr[12] + gD.y * wr[13] + gD.z * wr[14] + gD.w * wr[15];
            float acc = fmaf(rdegL[j], (m0 + m1) + (m2 + m3), brn);
            if (flL[j]) h += 0.1f * acc / (1.0f + __expf(-acc));
            hreg[j] = h;
        }
        hlast[b * DN + dn] = h;

        // tail: histT (s-contiguous global), y outputs (wave shuffles)
        {
            ushort16* ht = histT + ((size_t)b * DN + dn) * S + cb;
            #pragma unroll
            for (int qi = 0; qi < 4; ++qi) {
                uint4 q;
                q.x = pk2(hreg[qi * 8 + 0], hreg[qi * 8 + 1]);
                q.y = pk2(hreg[qi * 8 + 2], hreg[qi * 8 + 3]);
                q.z = pk2(hreg[qi * 8 + 4], hreg[qi * 8 + 5]);
                q.w = pk2(hreg[qi * 8 + 6], hreg[qi * 8 + 7]);
                *(uint4*)(ht + qi * 8) = q;
            }
        }
        size_t baseTD = ((size_t)(b * S + cb)) * DI + d;
        #pragma unroll
        for (int j = 0; j < CHUNK; ++j) {
            float rs = hreg[j] * CnL[j * 16 + n];
            rs += __shfl_xor(rs, 1);
            rs += __shfl_xor(rs, 2);
            rs += __shfl_xor(rs, 4);
            rs += __shfl_xor(rs, 8);
            if (n == 0) {
                float zv = zs[baseTD + (size_t)j * DI];
                yzb[baseTD + (size_t)j * DI] = f2bf(rs * zv);
            }
        }

        // G_new for chunk c+1 via MFMA: Gnew[jj][dn] = adjN[jj][sp] * h[sp][dn]
        if (c < NCHUNK - 1) {
            // write hreg transposed to hT (seg-major, conflict-free b128)
            #pragma unroll
            for (int seg = 0; seg < 4; ++seg) {
                uint4 q;
                q.x = pk2(hreg[seg * 8 + 0], hreg[seg * 8 + 1]);
                q.y = pk2(hreg[seg * 8 + 2], hreg[seg * 8 + 3]);
                q.z = pk2(hreg[seg * 8 + 4], hreg[seg * 8 + 5]);
                q.w = pk2(hreg[seg * 8 + 6], hreg[seg * 8 + 7]);
                *(uint4*)&hT[seg * 1024 + tid * 8] = q;
            }
            // stage adjN rows (chunk c+1 targets) as bf16
            {
                int j = tid >> 2, s8 = (tid & 3) * 8;
                const float* arow = adj + ((size_t)(b * S + cb + CHUNK + j)) * S + cb + s8;
                float4 a0 = *(const float4*)arow;
                float4 a1 = *(const float4*)(arow + 4);
                uint4 q;
                q.x = pk2(a0.x, a0.y); q.y = pk2(a0.z, a0.w);
                q.z = pk2(a1.x, a1.y); q.w = pk2(a1.z, a1.w);
                *(uint4*)&AsN[j * 40 + s8] = q;
            }
            __syncthreads();
            int w = tid >> 6, l = tid & 63;
            bf16x8 aF0 = *(const bf16x8*)&AsN[(l & 15) * 40 + (l >> 4) * 8];
            bf16x8 aF1 = *(const bf16x8*)&AsN[(16 + (l & 15)) * 40 + (l >> 4) * 8];
            ushort16* gw = Gnew + (size_t)((c + 1) & 1) * GBUF;
            int dnbase = (blockIdx.x & 63) << 7;    // block's global dn base
            #pragma unroll
            for (int dblk = 0; dblk < 4; ++dblk) {
                int col = w * 64 + dblk * 16 + (l & 15);
                bf16x8 bF = *(const bf16x8*)&hT[(l >> 4) * 1024 + col * 8];
                f32x4 a0v = {0.f, 0.f, 0.f, 0.f};
                f32x4 a1v = {0.f, 0.f, 0.f, 0.f};
                a0v = __builtin_amdgcn_mfma_f32_16x16x32_bf16(aF0, bF, a0v, 0, 0, 0);
                a1v = __builtin_amdgcn_mfma_f32_16x16x32_bf16(aF1, bF, a1v, 0, 0, 0);
                int dng = dnbase + col;
                int jb0 = (l >> 4) * 4;
                uint2 o0, o1;
                o0.x = pk2(a0v[0], a0v[1]); o0.y = pk2(a0v[2], a0v[3]);
                o1.x = pk2(a1v[0], a1v[1]); o1.y = pk2(a1v[2], a1v[3]);
                *(uint2*)(gw + ((size_t)b * DN + dng) * 32 + jb0) = o0;
                *(uint2*)(gw + ((size_t)b * DN + dng) * 32 + 16 + jb0) = o1;
            }
        }
    } else {
        // ---------------- gpast role: Gold(c+1) via bf16 MFMA ----------------
        if (c == 0 || c >= NCHUNK - 1) return;
        __shared__ __align__(16) short As2[32 * 40];
        __shared__ __align__(16) short Ws2[128 * 40];
        int idx = blockIdx.x - 128;              // 0..127
        int b = idx >> 6;
        int dn0 = (idx & 63) * 128;
        int w = tid >> 6, l = tid & 63;

        f32x4 acc[8] = {};
        for (int ks = 0; ks < c; ++ks) {
            {
                int j = tid >> 2, s8 = (tid & 3) * 8;
                const float* arow = adj + ((size_t)(b * S + cb + CHUNK + j)) * S + ks * CHUNK + s8;
                float4 a0 = *(const float4*)arow;
                float4 a1 = *(const float4*)(arow + 4);
                uint4 q;
                q.x = pk2(a0.x, a0.y); q.y = pk2(a0.z, a0.w);
                q.z = pk2(a1.x, a1.y); q.w = pk2(a1.z, a1.w);
                *(uint4*)&As2[j * 40 + s8] = q;
                #pragma unroll
                for (int seg = 0; seg < 4; ++seg)
                    *(uint4*)&Ws2[tid * 40 + seg * 8] =
                        *(const uint4*)(histT + ((size_t)b * DN + dn0 + tid) * S + ks * CHUNK + seg * 8);
            }
            __syncthreads();
            bf16x8 aF = *(const bf16x8*)&As2[(w * 16 + (l & 15)) * 40 + (l >> 4) * 8];
            #pragma unroll
            for (int dblk = 0; dblk < 8; ++dblk) {
                bf16x8 bF = *(const bf16x8*)&Ws2[(dblk * 16 + (l & 15)) * 40 + (l >> 4) * 8];
                acc[dblk] = __builtin_amdgcn_mfma_f32_16x16x32_bf16(aF, bF, acc[dblk], 0, 0, 0);
            }
            __syncthreads();
        }
        int jb = w * 16 + (l >> 4) * 4;
        ushort16* gbase = Gold + (size_t)((c + 1) & 1) * GBUF;
        #pragma unroll
        for (int dblk = 0; dblk < 8; ++dblk) {
            int dnc = dn0 + dblk * 16 + (l & 15);
            uint2 o;
            o.x = pk2(acc[dblk][0], acc[dblk][1]);
            o.y = pk2(acc[dblk][2], acc[dblk][3]);
            *(uint2*)(gbase + ((size_t)b * DN + dnc) * 32 + jb) = o;
        }
    }
}

// ---------------- launch ----------------
extern "C" void kernel_launch(void* const* d_in, const int* in_sizes, int n_in,
                              void* d_out, int out_size, void* d_ws, size_t ws_size,
                              hipStream_t stream) {
    const float* x      = (const float*)d_in[0];
    const float* adj    = (const float*)d_in[1];
    const float* ln_w   = (const float*)d_in[2];
    const float* ln_b   = (const float*)d_in[3];
    const float* W_in   = (const float*)d_in[4];
    const float* conv_w = (const float*)d_in[5];
    const float* conv_b = (const float*)d_in[6];
    const float* W_xp   = (const float*)d_in[7];
    const float* W_dt   = (const float*)d_in[8];
    const float* b_dt   = (const float*)d_in[9];
    const float* Wr     = (const float*)d_in[10];
    const float* br     = (const float*)d_in[11];
    const float* W_out  = (const float*)d_in[12];
    float* out = (float*)d_out;

    float* ws = (float*)d_ws;
    size_t off = 0;
    float* xz     = ws + off; off += (size_t)B * S * 2 * DI;
    float* x_act  = ws + off; off += (size_t)B * S * DI;
    float* dt_raw = ws + off; off += (size_t)B * S;
    float* Bmb    = ws + off; off += (size_t)B * S * N;
    float* Cmb    = ws + off; off += (size_t)B * S * N;
    float* rdegp  = ws + off; off += (size_t)B * S;
    int*   flagI  = (int*)(ws + off); off += S;
    float* Ebuf   = ws + off; off += (size_t)B * S * DI;
    float* zsbuf  = ws + off; off += (size_t)B * S * DI;
    float* hlast  = ws + off; off += (size_t)B * DN;
    ushort16* xnb    = (ushort16*)(ws + off); off += (size_t)B * S * D / 2;
    ushort16* yzb    = (ushort16*)(ws + off); off += (size_t)B * S * DI / 2;
    ushort16* histT  = (ushort16*)(ws + off); off += (size_t)B * DN * S / 2;
    ushort16* Gold   = (ushort16*)(ws + off); off += (size_t)2 * B * DN * 32 / 2;
    ushort16* Gnew   = (ushort16*)(ws + off); off += (size_t)2 * B * DN * 32 / 2;
    ushort16* xpb    = (ushort16*)(ws + off); off += (size_t)B * (S + 3) * DI / 2;
    ushort16* W_inb  = (ushort16*)(ws + off); off += (size_t)2 * DI * D / 2;
    ushort16* W_outb = (ushort16*)(ws + off); off += (size_t)D * DI / 2;

    hipMemsetAsync(flagI, 0, S * sizeof(int), stream);
    hipMemsetAsync(xpb, 0, (size_t)B * (S + 3) * DI * 2, stream);

    ln_k<<<B * S, 64, 0, stream>>>(x, ln_w, ln_b, xnb);
    wcast_k<<<(2 * DI * D) / 1024, 256, 0, stream>>>(W_in, W_inb);
    wcast_k<<<(D * DI) / 1024, 256, 0, stream>>>(W_out, W_outb);
    gemmb_k<<<dim3(2 * DI / 64, B * S / 64), 256, 0, stream>>>(xnb, W_inb, nullptr, xz, B * S, 2 * DI, D);
    cast_k<<<B * S * DI / (256 * 8), 256, 0, stream>>>(xz, xpb);
    convm_k<<<dim3(DI / 32, B * S / 32), 256, 0, stream>>>(xpb, conv_w, conv_b, x_act);
    ssm_k<<<B * S / 4, 256, 0, stream>>>(x_act, W_xp, dt_raw, Bmb, Cmb);
    deg_k<<<B * S, 64, 0, stream>>>(adj, rdegp, flagI);
    ez_k<<<B * S * DI / 256, 256, 0, stream>>>(dt_raw, W_dt, b_dt, xz, Ebuf, zsbuf);

    for (int c = 0; c < NCHUNK; ++c)
        chunk_k<<<256, 128, 0, stream>>>(adj, x_act, Ebuf, Bmb, Cmb, rdegp, flagI,
                                         Wr, br, Gold, Gnew, histT, hlast, zsbuf, yzb, c);

    gemmb_k<<<dim3(D / 64, B * S / 64), 256, 0, stream>>>(yzb, W_outb, x, out, B * S, D, DI);
}

// Round 10
// 334.993 us; speedup vs baseline: 3.4800x; 1.4654x over previous
//
#include <hip/hip_runtime.h>
#include <math.h>

// Problem constants
static constexpr int B  = 2;
static constexpr int S  = 512;
static constexpr int D  = 256;
static constexpr int N  = 16;
static constexpr int DI = 512;
static constexpr int CHUNK = 32;
static constexpr int NCHUNK = S / CHUNK;   // 16
static constexpr int DN = DI * N;          // 8192

typedef unsigned int uint32;
typedef unsigned short ushort16;
using bf16x8 = __attribute__((ext_vector_type(8))) short;
using f32x4  = __attribute__((ext_vector_type(4))) float;

__device__ __forceinline__ ushort16 f2bf(float f) {
    uint32 u = __float_as_uint(f);
    u = (u + 0x7fffu + ((u >> 16) & 1u)) >> 16;   // RNE
    return (ushort16)u;
}
__device__ __forceinline__ float bflo(uint32 u) { return __uint_as_float(u << 16); }
__device__ __forceinline__ float bfhi(uint32 u) { return __uint_as_float(u & 0xffff0000u); }
__device__ __forceinline__ float bf2f(ushort16 u) { return __uint_as_float(((uint32)u) << 16); }
__device__ __forceinline__ uint32 pk2(float a, float b) {
    return (uint32)(ushort16)f2bf(a) | ((uint32)(ushort16)f2bf(b) << 16);
}

// ---------------- LayerNorm: one wave per row, bf16 output ----------------
__global__ void ln_k(const float* __restrict__ x, const float* __restrict__ w,
                     const float* __restrict__ bias, ushort16* __restrict__ xnb) {
    int row = blockIdx.x;
    int lane = threadIdx.x;
    float4 v = *(const float4*)(x + row * D + lane * 4);
    float s = v.x + v.y + v.z + v.w;
    float q = v.x * v.x + v.y * v.y + v.z * v.z + v.w * v.w;
    for (int m = 1; m < 64; m <<= 1) { s += __shfl_xor(s, m); q += __shfl_xor(q, m); }
    float mu  = s * (1.0f / D);
    float var = q * (1.0f / D) - mu * mu;
    float rs  = rsqrtf(var + 1e-5f);
    float4 wv = *(const float4*)(w + lane * 4);
    float4 bv = *(const float4*)(bias + lane * 4);
    float4 o;
    o.x = (v.x - mu) * rs * wv.x + bv.x;
    o.y = (v.y - mu) * rs * wv.y + bv.y;
    o.z = (v.z - mu) * rs * wv.z + bv.z;
    o.w = (v.w - mu) * rs * wv.w + bv.w;
    uint2 pk;
    pk.x = pk2(o.x, o.y);
    pk.y = pk2(o.z, o.w);
    *(uint2*)(xnb + row * D + lane * 4) = pk;
}

// ---------------- generic f32 -> bf16 cast ----------------
__global__ void wcast_k(const float* __restrict__ src, ushort16* __restrict__ dst) {
    int i = blockIdx.x * 256 + threadIdx.x;
    float4 v = *(const float4*)(src + (size_t)i * 4);
    uint2 pk;
    pk.x = pk2(v.x, v.y);
    pk.y = pk2(v.z, v.w);
    *(uint2*)(dst + (size_t)i * 4) = pk;
}

// ---------------- bf16 MFMA GEMM: C[M,Nc] = A[M,K] @ W[Nc,K]^T (+res, f32 out) -------
__global__ __launch_bounds__(256) void gemmb_k(const ushort16* __restrict__ A,
                                               const ushort16* __restrict__ W,
                                               const float* __restrict__ res,
                                               float* __restrict__ C,
                                               int M, int Nc, int K) {
    __shared__ __align__(16) short As[64 * 40];
    __shared__ __align__(16) short Ws[64 * 40];
    int tid = threadIdx.x;
    int l = tid & 63, wid = tid >> 6;
    int wm = wid & 1, wn = wid >> 1;
    int row0 = blockIdx.y * 64, col0 = blockIdx.x * 64;
    int r = tid >> 2, kseg = (tid & 3) * 8;
    f32x4 acc[2][2] = {};
    for (int k0 = 0; k0 < K; k0 += 32) {
        *(uint4*)&As[r * 40 + kseg] = *(const uint4*)(A + (size_t)(row0 + r) * K + k0 + kseg);
        *(uint4*)&Ws[r * 40 + kseg] = *(const uint4*)(W + (size_t)(col0 + r) * K + k0 + kseg);
        __syncthreads();
        bf16x8 aF[2], bF[2];
        #pragma unroll
        for (int am = 0; am < 2; ++am)
            aF[am] = *(const bf16x8*)&As[(wm * 32 + am * 16 + (l & 15)) * 40 + (l >> 4) * 8];
        #pragma unroll
        for (int bn = 0; bn < 2; ++bn)
            bF[bn] = *(const bf16x8*)&Ws[(wn * 32 + bn * 16 + (l & 15)) * 40 + (l >> 4) * 8];
        #pragma unroll
        for (int am = 0; am < 2; ++am)
            #pragma unroll
            for (int bn = 0; bn < 2; ++bn)
                acc[am][bn] = __builtin_amdgcn_mfma_f32_16x16x32_bf16(aF[am], bF[bn], acc[am][bn], 0, 0, 0);
        __syncthreads();
    }
    #pragma unroll
    for (int am = 0; am < 2; ++am)
        #pragma unroll
        for (int bn = 0; bn < 2; ++bn) {
            int cc = col0 + wn * 32 + bn * 16 + (l & 15);
            #pragma unroll
            for (int reg = 0; reg < 4; ++reg) {
                int rr = row0 + wm * 32 + am * 16 + (l >> 4) * 4 + reg;
                float v = acc[am][bn][reg];
                if (res) v += res[(size_t)rr * Nc + cc];
                C[(size_t)rr * Nc + cc] = v;
            }
        }
}

// ---------------- cast xz[:, :DI] -> xpb (bf16, with 3-row zero halo per batch) -------
__global__ void cast_k(const float* __restrict__ xz, ushort16* __restrict__ xpb) {
    int i = blockIdx.x * 256 + threadIdx.x;
    int row = i >> 6;
    int off = (i & 63) * 8;
    int b = row >> 9, t = row & (S - 1);
    float4 v0 = *(const float4*)(xz + (size_t)row * (2 * DI) + off);
    float4 v1 = *(const float4*)(xz + (size_t)row * (2 * DI) + off + 4);
    uint4 pk;
    pk.x = pk2(v0.x, v0.y);
    pk.y = pk2(v0.z, v0.w);
    pk.z = pk2(v1.x, v1.y);
    pk.w = pk2(v1.z, v1.w);
    *(uint4*)(xpb + ((size_t)(b * (S + 3) + 3 + t)) * DI + off) = pk;
}

// ---------------- Causal conv via bf16 MFMA + bias + silu ----------------
__global__ __launch_bounds__(256) void convm_k(const ushort16* __restrict__ xpb,
                                               const float* __restrict__ conv_w,
                                               const float* __restrict__ conv_b,
                                               float* __restrict__ x_act) {
    __shared__ __align__(16) short AxS[35 * 40];
    __shared__ __align__(16) short WbS[4 * 32 * 40];
    int tid = threadIdx.x;
    int l = tid & 63, wid = tid >> 6;
    int wm = wid & 1, wn = wid >> 1;
    int o0 = blockIdx.x * 32;
    int mt = blockIdx.y;
    int b = mt >> 4, tl0 = (mt & 15) * 32;
    f32x4 acc = {0.f, 0.f, 0.f, 0.f};

    for (int k0 = 0; k0 < DI; k0 += 32) {
        if (tid < 140) {
            int rr = tid >> 2, seg = tid & 3;
            uint4 v = *(const uint4*)(xpb + ((size_t)(b * (S + 3) + tl0 + rr)) * DI + k0 + seg * 8);
            *(uint4*)&AxS[rr * 40 + seg * 8] = v;
        }
        #pragma unroll
        for (int it = 0; it < 4; ++it) {
            int p = it * 256 + tid;
            int o = p >> 5, i = p & 31;
            float4 w4 = *(const float4*)(conv_w + ((size_t)(o0 + o) * DI + (k0 + i)) * 4);
            WbS[(0 * 32 + o) * 40 + i] = (short)f2bf(w4.x);
            WbS[(1 * 32 + o) * 40 + i] = (short)f2bf(w4.y);
            WbS[(2 * 32 + o) * 40 + i] = (short)f2bf(w4.z);
            WbS[(3 * 32 + o) * 40 + i] = (short)f2bf(w4.w);
        }
        __syncthreads();
        #pragma unroll
        for (int k = 0; k < 4; ++k) {
            bf16x8 aF = *(const bf16x8*)&AxS[(wm * 16 + (l & 15) + k) * 40 + (l >> 4) * 8];
            bf16x8 bF = *(const bf16x8*)&WbS[(k * 32 + wn * 16 + (l & 15)) * 40 + (l >> 4) * 8];
            acc = __builtin_amdgcn_mfma_f32_16x16x32_bf16(aF, bF, acc, 0, 0, 0);
        }
        __syncthreads();
    }
    int oc = o0 + wn * 16 + (l & 15);
    float bia = conv_b[oc];
    #pragma unroll
    for (int reg = 0; reg < 4; ++reg) {
        int m = wm * 16 + (l >> 4) * 4 + reg;
        float v = acc[reg] + bia;
        x_act[((size_t)(b * S + tl0 + m)) * DI + oc] = v / (1.0f + __expf(-v));
    }
}

// ---------------- ssm = x_act @ W_xp^T (33 outputs) ----------------
__global__ void ssm_k(const float* __restrict__ x_act, const float* __restrict__ W_xp,
                      float* __restrict__ dt_raw, float* __restrict__ Bm, float* __restrict__ Cm) {
    int row = blockIdx.x * 4 + (threadIdx.x >> 6);
    int lane = threadIdx.x & 63;
    const float* xr = x_act + (size_t)row * DI + lane * 8;
    float4 v0 = *(const float4*)xr;
    float4 v1 = *(const float4*)(xr + 4);
    for (int j = 0; j < 2 * N + 1; ++j) {
        const float* wr = W_xp + (size_t)j * DI + lane * 8;
        float4 w0 = *(const float4*)wr;
        float4 w1 = *(const float4*)(wr + 4);
        float acc = v0.x * w0.x + v0.y * w0.y + v0.z * w0.z + v0.w * w0.w
                  + v1.x * w1.x + v1.y * w1.y + v1.z * w1.z + v1.w * w1.w;
        for (int m = 1; m < 64; m <<= 1) acc += __shfl_xor(acc, m);
        if (lane == 0) {
            if (j == 0)           dt_raw[row] = acc;
            else if (j < 1 + N)   Bm[(size_t)row * N + (j - 1)] = acc;
            else                  Cm[(size_t)row * N + (j - 1 - N)] = acc;
        }
    }
}

// ---------------- rdeg = 1/max(sum_{s<t} adj,1); flag[t] ----------------
__global__ void deg_k(const float* __restrict__ adj, float* __restrict__ rdeg, int* __restrict__ flagI) {
    int t = blockIdx.x & (S - 1), b = blockIdx.x >> 9;
    int lane = threadIdx.x;
    const float* row = adj + ((size_t)(b * S + t)) * S;
    float s = 0.0f; bool anyp = false;
    for (int i = lane; i < t; i += 64) { float v = row[i]; s += v; anyp |= (v > 0.0f); }
    for (int m = 1; m < 64; m <<= 1) s += __shfl_xor(s, m);
    bool any = __any(anyp);
    if (lane == 0) {
        rdeg[b * S + t] = 1.0f / fmaxf(s, 1.0f);
        if (t > 0 && any) atomicOr(flagI + t, 1);
    }
}

// ---------------- E = exp(-softplus(dt)), zs = silu(z) ----------------
__global__ void ez_k(const float* __restrict__ dt_raw, const float* __restrict__ W_dt,
                     const float* __restrict__ b_dt, const float* __restrict__ xz,
                     float* __restrict__ E, float* __restrict__ zs) {
    int i = blockIdx.x * 256 + threadIdx.x;
    int d = i & (DI - 1);
    int row = i >> 9;
    float vv = dt_raw[row] * W_dt[d] + b_dt[d];
    E[i] = 1.0f / (1.0f + __expf(vv));
    float z = xz[(size_t)row * (2 * DI) + DI + d];
    zs[i] = z / (1.0f + __expf(-z));
}

// ================= fused chunk kernel (128-thread blocks, 384 blocks) =================
// histT: bf16 [b][dn][s]; Gold1/Gold2/Gnew: bf16 [parity][b][dn][j32]
// blocks [0,128):   scan role: 8 d-groups x 16 n = 128 lanes (2 waves/CU).
// blocks [128,384): gpast role, 2 ks-halves: Gold1(c+1)=chunks [0,c/2),
//                   Gold2(c+1)=chunks [c/2,c). MFMA over histT.
__global__ __launch_bounds__(128) void chunk_k(const float* __restrict__ adj,
                                               const float* __restrict__ x_act,
                                               const float* __restrict__ E,
                                               const float* __restrict__ Bm,
                                               const float* __restrict__ rdeg,
                                               const int* __restrict__ flagI,
                                               const float* __restrict__ Wr,
                                               const float* __restrict__ br,
                                               ushort16* __restrict__ Gold1,
                                               ushort16* __restrict__ Gold2,
                                               ushort16* __restrict__ Gnew,
                                               ushort16* __restrict__ histT,
                                               float* __restrict__ hlast, int c) {
    int tid = threadIdx.x;
    int cb = c * CHUNK;
    const size_t GBUF = (size_t)B * DN * 32;   // ushorts per parity

    if (blockIdx.x < 128) {
        // ---------------- scan role ----------------
        __shared__ float adjblk[32 * 36];           // f32 triangle, stride 36
        __shared__ float eL[32 * 8];
        __shared__ float xaL[32 * 8];
        __shared__ float BnL[32 * 16];
        __shared__ float rdegL[32];
        __shared__ int   flL[32];
        __shared__ float gx[128];
        __shared__ __align__(16) short hT[4 * 128 * 8];   // seg-major [kseg][dn][8sp]
        __shared__ __align__(16) short AsN[32 * 40];      // adjN bf16, stride 40

        int b = blockIdx.x >> 6;
        int d0 = (blockIdx.x & 63) << 3;
        int n = tid & 15, grp = tid >> 4;          // grp 0..7
        int d = d0 + grp;
        int dn = d * N + n;

        // stage (coalesced)
        {
            int j = tid >> 2;
            int s8 = (tid & 3) * 8;
            const float* arow = adj + ((size_t)(b * S + cb + j)) * S + cb + s8;
            float4 a0 = *(const float4*)arow;
            float4 a1 = *(const float4*)(arow + 4);
            float* dstp = adjblk + j * 36 + s8;
            dstp[0] = a0.x; dstp[1] = a0.y; dstp[2] = a0.z; dstp[3] = a0.w;
            dstp[4] = a1.x; dstp[5] = a1.y; dstp[6] = a1.z; dstp[7] = a1.w;
            if (c < NCHUNK - 1) {
                const float* arowN = adj + ((size_t)(b * S + cb + CHUNK + j)) * S + cb + s8;
                float4 n0 = *(const float4*)arowN;
                float4 n1 = *(const float4*)(arowN + 4);
                uint4 q;
                q.x = pk2(n0.x, n0.y); q.y = pk2(n0.z, n0.w);
                q.z = pk2(n1.x, n1.y); q.w = pk2(n1.z, n1.w);
                *(uint4*)&AsN[j * 40 + s8] = q;
            }
            int dd = (tid & 3) * 2;
            float2 ev = *(const float2*)(E     + ((size_t)(b * S + cb + j)) * DI + d0 + dd);
            float2 xv = *(const float2*)(x_act + ((size_t)(b * S + cb + j)) * DI + d0 + dd);
            eL [j * 8 + dd] = ev.x; eL [j * 8 + dd + 1] = ev.y;
            xaL[j * 8 + dd] = xv.x; xaL[j * 8 + dd + 1] = xv.y;
            int nn = (tid & 3) * 4;
            float4 bv = *(const float4*)(Bm + ((size_t)(b * S + cb + j)) * N + nn);
            BnL[j * 16 + nn] = bv.x; BnL[j * 16 + nn + 1] = bv.y;
            BnL[j * 16 + nn + 2] = bv.z; BnL[j * 16 + nn + 3] = bv.w;
            if (tid < 32) {
                rdegL[tid] = rdeg[b * S + cb + tid];
                flL[tid]   = flagI[cb + tid];
            }
        }

        // presum Gnew + Gold1 + Gold2 into registers
        float gsum[CHUNK];
        #pragma unroll
        for (int j = 0; j < CHUNK; ++j) gsum[j] = 0.0f;
        if (c >= 1) {
            const ushort16* gp = Gnew + (size_t)(c & 1) * GBUF + ((size_t)b * DN + dn) * 32;
            #pragma unroll
            for (int qi = 0; qi < 4; ++qi) {
                uint4 q = *(const uint4*)(gp + qi * 8);
                gsum[qi * 8 + 0] += bflo(q.x); gsum[qi * 8 + 1] += bfhi(q.x);
                gsum[qi * 8 + 2] += bflo(q.y); gsum[qi * 8 + 3] += bfhi(q.y);
                gsum[qi * 8 + 4] += bflo(q.z); gsum[qi * 8 + 5] += bfhi(q.z);
                gsum[qi * 8 + 6] += bflo(q.w); gsum[qi * 8 + 7] += bfhi(q.w);
            }
        }
        if (c >= 2) {
            const ushort16* gp = Gold2 + (size_t)(c & 1) * GBUF + ((size_t)b * DN + dn) * 32;
            #pragma unroll
            for (int qi = 0; qi < 4; ++qi) {
                uint4 q = *(const uint4*)(gp + qi * 8);
                gsum[qi * 8 + 0] += bflo(q.x); gsum[qi * 8 + 1] += bfhi(q.x);
                gsum[qi * 8 + 2] += bflo(q.y); gsum[qi * 8 + 3] += bfhi(q.y);
                gsum[qi * 8 + 4] += bflo(q.z); gsum[qi * 8 + 5] += bfhi(q.z);
                gsum[qi * 8 + 6] += bflo(q.w); gsum[qi * 8 + 7] += bfhi(q.w);
            }
        }
        if (c >= 3) {
            const ushort16* gp = Gold1 + (size_t)(c & 1) * GBUF + ((size_t)b * DN + dn) * 32;
            #pragma unroll
            for (int qi = 0; qi < 4; ++qi) {
                uint4 q = *(const uint4*)(gp + qi * 8);
                gsum[qi * 8 + 0] += bflo(q.x); gsum[qi * 8 + 1] += bfhi(q.x);
                gsum[qi * 8 + 2] += bflo(q.y); gsum[qi * 8 + 3] += bfhi(q.y);
                gsum[qi * 8 + 4] += bflo(q.z); gsum[qi * 8 + 5] += bfhi(q.z);
                gsum[qi * 8 + 6] += bflo(q.w); gsum[qi * 8 + 7] += bfhi(q.w);
            }
        }

        float wr[16];
        #pragma unroll
        for (int m = 0; m < 16; ++m) wr[m] = Wr[n * 16 + m];
        float brn = br[n];
        float h = (c == 0) ? 0.0f : hlast[b * DN + dn];
        __syncthreads();

        float hreg[CHUNK];
        #pragma unroll
        for (int j = 0; j < CHUNK; ++j) {
            float e  = eL [j * 8 + grp];
            float xa = xaL[j * 8 + grp];
            float Bn = BnL[j * 16 + n];
            h = h * e + xa * Bn;

            // triangle via float4 broadcast reads
            float g0 = gsum[j], g1 = 0.0f, g2 = 0.0f, g3 = 0.0f;
            const float* ar = adjblk + j * 36;
            int sp = 0;
            #pragma unroll
            for (; sp + 4 <= j; sp += 4) {
                float4 av = *(const float4*)(ar + sp);
                g0 += av.x * hreg[sp];     g1 += av.y * hreg[sp + 1];
                g2 += av.z * hreg[sp + 2]; g3 += av.w * hreg[sp + 3];
            }
            #pragma unroll
            for (; sp < j; ++sp) g0 += ar[sp] * hreg[sp];
            float gr = (g0 + g1) + (g2 + g3);

            // Wr-mix via LDS round-trip
            gx[tid] = gr;
            __threadfence_block();
            float4 gA = *(const float4*)&gx[grp * 16];
            float4 gB = *(const float4*)&gx[grp * 16 + 4];
            float4 gC = *(const float4*)&gx[grp * 16 + 8];
            float4 gD = *(const float4*)&gx[grp * 16 + 12];
            float m0 = gA.x * wr[0]  + gA.y * wr[1]  + gA.z * wr[2]  + gA.w * wr[3];
            float m1 = gB.x * wr[4]  + gB.y * wr[5]  + gB.z * wr[6]  + gB.w * wr[7];
            float m2 = gC.x * wr[8]  + gC.y * wr[9]  + gC.z * wr[10] + gC.w * wr[11];
            float m3 = gD.x * wr[12] + gD.y * wr[13] + gD.z * wr[14] + gD.w * wr[15];
            float acc = fmaf(rdegL[j], (m0 + m1) + (m2 + m3), brn);
            if (flL[j]) h += 0.1f * acc / (1.0f + __expf(-acc));
            hreg[j] = h;
        }
        hlast[b * DN + dn] = h;

        // tail: histT (s-contiguous global)
        {
            ushort16* ht = histT + ((size_t)b * DN + dn) * S + cb;
            #pragma unroll
            for (int qi = 0; qi < 4; ++qi) {
                uint4 q;
                q.x = pk2(hreg[qi * 8 + 0], hreg[qi * 8 + 1]);
                q.y = pk2(hreg[qi * 8 + 2], hreg[qi * 8 + 3]);
                q.z = pk2(hreg[qi * 8 + 4], hreg[qi * 8 + 5]);
                q.w = pk2(hreg[qi * 8 + 6], hreg[qi * 8 + 7]);
                *(uint4*)(ht + qi * 8) = q;
            }
        }

        // G_new for chunk c+1 via MFMA: Gnew[jj][dn] = adjN[jj][sp] * h[sp][dn]
        if (c < NCHUNK - 1) {
            #pragma unroll
            for (int seg = 0; seg < 4; ++seg) {
                uint4 q;
                q.x = pk2(hreg[seg * 8 + 0], hreg[seg * 8 + 1]);
                q.y = pk2(hreg[seg * 8 + 2], hreg[seg * 8 + 3]);
                q.z = pk2(hreg[seg * 8 + 4], hreg[seg * 8 + 5]);
                q.w = pk2(hreg[seg * 8 + 6], hreg[seg * 8 + 7]);
                *(uint4*)&hT[seg * 1024 + tid * 8] = q;
            }
            __syncthreads();
            int w = tid >> 6, l = tid & 63;
            bf16x8 aF0 = *(const bf16x8*)&AsN[(l & 15) * 40 + (l >> 4) * 8];
            bf16x8 aF1 = *(const bf16x8*)&AsN[(16 + (l & 15)) * 40 + (l >> 4) * 8];
            ushort16* gw = Gnew + (size_t)((c + 1) & 1) * GBUF;
            int dnbase = (blockIdx.x & 63) << 7;
            #pragma unroll
            for (int dblk = 0; dblk < 4; ++dblk) {
                int col = w * 64 + dblk * 16 + (l & 15);
                bf16x8 bF = *(const bf16x8*)&hT[(l >> 4) * 1024 + col * 8];
                f32x4 a0v = {0.f, 0.f, 0.f, 0.f};
                f32x4 a1v = {0.f, 0.f, 0.f, 0.f};
                a0v = __builtin_amdgcn_mfma_f32_16x16x32_bf16(aF0, bF, a0v, 0, 0, 0);
                a1v = __builtin_amdgcn_mfma_f32_16x16x32_bf16(aF1, bF, a1v, 0, 0, 0);
                int dng = dnbase + col;
                int jb0 = (l >> 4) * 4;
                uint2 o0, o1;
                o0.x = pk2(a0v[0], a0v[1]); o0.y = pk2(a0v[2], a0v[3]);
                o1.x = pk2(a1v[0], a1v[1]); o1.y = pk2(a1v[2], a1v[3]);
                *(uint2*)(gw + ((size_t)b * DN + dng) * 32 + jb0) = o0;
                *(uint2*)(gw + ((size_t)b * DN + dng) * 32 + 16 + jb0) = o1;
            }
        }
    } else {
        // ---------------- gpast role: Gold1/Gold2(c+1) via bf16 MFMA ----------------
        if (c == 0 || c >= NCHUNK - 1) return;
        __shared__ __align__(16) short As2[32 * 40];
        __shared__ __align__(16) short Ws2[128 * 40];
        int idx = blockIdx.x - 128;              // 0..255
        int tile = idx & 63;
        int b = (idx >> 6) & 1;
        int half = idx >> 7;
        int ks0 = half ? (c >> 1) : 0;
        int ks1 = half ? c : (c >> 1);
        if (ks0 >= ks1) return;
        int dn0 = tile * 128;
        int w = tid >> 6, l = tid & 63;

        f32x4 acc[8] = {};
        for (int ks = ks0; ks < ks1; ++ks) {
            {
                int j = tid >> 2, s8 = (tid & 3) * 8;
                const float* arow = adj + ((size_t)(b * S + cb + CHUNK + j)) * S + ks * CHUNK + s8;
                float4 a0 = *(const float4*)arow;
                float4 a1 = *(const float4*)(arow + 4);
                uint4 q;
                q.x = pk2(a0.x, a0.y); q.y = pk2(a0.z, a0.w);
                q.z = pk2(a1.x, a1.y); q.w = pk2(a1.z, a1.w);
                *(uint4*)&As2[j * 40 + s8] = q;
                #pragma unroll
                for (int seg = 0; seg < 4; ++seg)
                    *(uint4*)&Ws2[tid * 40 + seg * 8] =
                        *(const uint4*)(histT + ((size_t)b * DN + dn0 + tid) * S + ks * CHUNK + seg * 8);
            }
            __syncthreads();
            bf16x8 aF = *(const bf16x8*)&As2[(w * 16 + (l & 15)) * 40 + (l >> 4) * 8];
            #pragma unroll
            for (int dblk = 0; dblk < 8; ++dblk) {
                bf16x8 bF = *(const bf16x8*)&Ws2[(dblk * 16 + (l & 15)) * 40 + (l >> 4) * 8];
                acc[dblk] = __builtin_amdgcn_mfma_f32_16x16x32_bf16(aF, bF, acc[dblk], 0, 0, 0);
            }
            __syncthreads();
        }
        int jb = w * 16 + (l >> 4) * 4;
        ushort16* gbase = (half ? Gold2 : Gold1) + (size_t)((c + 1) & 1) * GBUF;
        #pragma unroll
        for (int dblk = 0; dblk < 8; ++dblk) {
            int dnc = dn0 + dblk * 16 + (l & 15);
            uint2 o;
            o.x = pk2(acc[dblk][0], acc[dblk][1]);
            o.y = pk2(acc[dblk][2], acc[dblk][3]);
            *(uint2*)(gbase + ((size_t)b * DN + dnc) * 32 + jb) = o;
        }
    }
}

// ---------------- y_k: y[b,t,d] = (sum_n histT[b][dn][t]*Cm[b,t,n]) * zs[b,t,d] -------
// block = (b,d); histT reads coalesced along s.
__global__ __launch_bounds__(256) void y_k(const ushort16* __restrict__ histT,
                                           const float* __restrict__ Cm,
                                           const float* __restrict__ zs,
                                           ushort16* __restrict__ yzb) {
    __shared__ float CmL[S * 17];    // [t][n], stride 17 (bank-spread)
    int b = blockIdx.x >> 9;
    int d = blockIdx.x & (DI - 1);
    int tid = threadIdx.x;
    #pragma unroll
    for (int q = 0; q < 8; ++q) {
        int l0 = q * 1024 + tid * 4;
        int t = l0 >> 4, n0 = l0 & 15;
        float4 v = *(const float4*)(Cm + (size_t)b * S * N + l0);
        CmL[t * 17 + n0]     = v.x;
        CmL[t * 17 + n0 + 1] = v.y;
        CmL[t * 17 + n0 + 2] = v.z;
        CmL[t * 17 + n0 + 3] = v.w;
    }
    __syncthreads();
    const ushort16* hbase = histT + ((size_t)b * DN + d * N) * S;
    #pragma unroll
    for (int pass = 0; pass < 2; ++pass) {
        int t = pass * 256 + tid;
        float a0 = 0.f, a1 = 0.f, a2 = 0.f, a3 = 0.f;
        #pragma unroll
        for (int n = 0; n < 16; n += 4) {
            a0 += bf2f(hbase[(size_t)n * S + t])       * CmL[t * 17 + n];
            a1 += bf2f(hbase[(size_t)(n + 1) * S + t]) * CmL[t * 17 + n + 1];
            a2 += bf2f(hbase[(size_t)(n + 2) * S + t]) * CmL[t * 17 + n + 2];
            a3 += bf2f(hbase[(size_t)(n + 3) * S + t]) * CmL[t * 17 + n + 3];
        }
        float acc = (a0 + a1) + (a2 + a3);
        float zv = zs[((size_t)(b * S + t)) * DI + d];
        yzb[((size_t)(b * S + t)) * DI + d] = f2bf(acc * zv);
    }
}

// ---------------- launch ----------------
extern "C" void kernel_launch(void* const* d_in, const int* in_sizes, int n_in,
                              void* d_out, int out_size, void* d_ws, size_t ws_size,
                              hipStream_t stream) {
    const float* x      = (const float*)d_in[0];
    const float* adj    = (const float*)d_in[1];
    const float* ln_w   = (const float*)d_in[2];
    const float* ln_b   = (const float*)d_in[3];
    const float* W_in   = (const float*)d_in[4];
    const float* conv_w = (const float*)d_in[5];
    const float* conv_b = (const float*)d_in[6];
    const float* W_xp   = (const float*)d_in[7];
    const float* W_dt   = (const float*)d_in[8];
    const float* b_dt   = (const float*)d_in[9];
    const float* Wr     = (const float*)d_in[10];
    const float* br     = (const float*)d_in[11];
    const float* W_out  = (const float*)d_in[12];
    float* out = (float*)d_out;

    float* ws = (float*)d_ws;
    size_t off = 0;
    float* xz     = ws + off; off += (size_t)B * S * 2 * DI;
    float* x_act  = ws + off; off += (size_t)B * S * DI;
    float* dt_raw = ws + off; off += (size_t)B * S;
    float* Bmb    = ws + off; off += (size_t)B * S * N;
    float* Cmb    = ws + off; off += (size_t)B * S * N;
    float* rdegp  = ws + off; off += (size_t)B * S;
    int*   flagI  = (int*)(ws + off); off += S;
    float* Ebuf   = ws + off; off += (size_t)B * S * DI;
    float* zsbuf  = ws + off; off += (size_t)B * S * DI;
    float* hlast  = ws + off; off += (size_t)B * DN;
    ushort16* xnb    = (ushort16*)(ws + off); off += (size_t)B * S * D / 2;
    ushort16* yzb    = (ushort16*)(ws + off); off += (size_t)B * S * DI / 2;
    ushort16* histT  = (ushort16*)(ws + off); off += (size_t)B * DN * S / 2;
    ushort16* Gold1  = (ushort16*)(ws + off); off += (size_t)2 * B * DN * 32 / 2;
    ushort16* Gold2  = (ushort16*)(ws + off); off += (size_t)2 * B * DN * 32 / 2;
    ushort16* Gnew   = (ushort16*)(ws + off); off += (size_t)2 * B * DN * 32 / 2;
    ushort16* xpb    = (ushort16*)(ws + off); off += (size_t)B * (S + 3) * DI / 2;
    ushort16* W_inb  = (ushort16*)(ws + off); off += (size_t)2 * DI * D / 2;
    ushort16* W_outb = (ushort16*)(ws + off); off += (size_t)D * DI / 2;

    hipMemsetAsync(flagI, 0, S * sizeof(int), stream);
    hipMemsetAsync(xpb, 0, (size_t)B * (S + 3) * DI * 2, stream);

    ln_k<<<B * S, 64, 0, stream>>>(x, ln_w, ln_b, xnb);
    wcast_k<<<(2 * DI * D) / 1024, 256, 0, stream>>>(W_in, W_inb);
    wcast_k<<<(D * DI) / 1024, 256, 0, stream>>>(W_out, W_outb);
    gemmb_k<<<dim3(2 * DI / 64, B * S / 64), 256, 0, stream>>>(xnb, W_inb, nullptr, xz, B * S, 2 * DI, D);
    cast_k<<<B * S * DI / (256 * 8), 256, 0, stream>>>(xz, xpb);
    convm_k<<<dim3(DI / 32, B * S / 32), 256, 0, stream>>>(xpb, conv_w, conv_b, x_act);
    ssm_k<<<B * S / 4, 256, 0, stream>>>(x_act, W_xp, dt_raw, Bmb, Cmb);
    deg_k<<<B * S, 64, 0, stream>>>(adj, rdegp, flagI);
    ez_k<<<B * S * DI / 256, 256, 0, stream>>>(dt_raw, W_dt, b_dt, xz, Ebuf, zsbuf);

    for (int c = 0; c < NCHUNK; ++c)
        chunk_k<<<384, 128, 0, stream>>>(adj, x_act, Ebuf, Bmb, rdegp, flagI,
                                         Wr, br, Gold1, Gold2, Gnew, histT, hlast, c);

    y_k<<<B * DI, 256, 0, stream>>>(histT, Cmb, zsbuf, yzb);

    gemmb_k<<<dim3(D / 64, B * S / 64), 256, 0, stream>>>(yzb, W_outb, x, out, B * S, D, DI);
}

// Round 11
// 315.353 us; speedup vs baseline: 3.6968x; 1.0623x over previous
//
#include <hip/hip_runtime.h>
#include <math.h>

// Problem constants
static constexpr int B  = 2;
static constexpr int S  = 512;
static constexpr int D  = 256;
static constexpr int N  = 16;
static constexpr int DI = 512;
static constexpr int CHUNK = 32;
static constexpr int NCHUNK = S / CHUNK;   // 16
static constexpr int NL = NCHUNK / 2;      // 8 launches, 2 chunks each
static constexpr int DN = DI * N;          // 8192

typedef unsigned int uint32;
typedef unsigned short ushort16;
using bf16x8 = __attribute__((ext_vector_type(8))) short;
using f32x4  = __attribute__((ext_vector_type(4))) float;

__device__ __forceinline__ ushort16 f2bf(float f) {
    uint32 u = __float_as_uint(f);
    u = (u + 0x7fffu + ((u >> 16) & 1u)) >> 16;   // RNE
    return (ushort16)u;
}
__device__ __forceinline__ float bflo(uint32 u) { return __uint_as_float(u << 16); }
__device__ __forceinline__ float bfhi(uint32 u) { return __uint_as_float(u & 0xffff0000u); }
__device__ __forceinline__ float bf2f(ushort16 u) { return __uint_as_float(((uint32)u) << 16); }
__device__ __forceinline__ uint32 pk2(float a, float b) {
    return (uint32)(ushort16)f2bf(a) | ((uint32)(ushort16)f2bf(b) << 16);
}

// ---------------- LayerNorm: one wave per row, bf16 output ----------------
__global__ void ln_k(const float* __restrict__ x, const float* __restrict__ w,
                     const float* __restrict__ bias, ushort16* __restrict__ xnb) {
    int row = blockIdx.x;
    int lane = threadIdx.x;
    float4 v = *(const float4*)(x + row * D + lane * 4);
    float s = v.x + v.y + v.z + v.w;
    float q = v.x * v.x + v.y * v.y + v.z * v.z + v.w * v.w;
    for (int m = 1; m < 64; m <<= 1) { s += __shfl_xor(s, m); q += __shfl_xor(q, m); }
    float mu  = s * (1.0f / D);
    float var = q * (1.0f / D) - mu * mu;
    float rs  = rsqrtf(var + 1e-5f);
    float4 wv = *(const float4*)(w + lane * 4);
    float4 bv = *(const float4*)(bias + lane * 4);
    float4 o;
    o.x = (v.x - mu) * rs * wv.x + bv.x;
    o.y = (v.y - mu) * rs * wv.y + bv.y;
    o.z = (v.z - mu) * rs * wv.z + bv.z;
    o.w = (v.w - mu) * rs * wv.w + bv.w;
    uint2 pk;
    pk.x = pk2(o.x, o.y);
    pk.y = pk2(o.z, o.w);
    *(uint2*)(xnb + row * D + lane * 4) = pk;
}

// ---------------- generic f32 -> bf16 cast ----------------
__global__ void wcast_k(const float* __restrict__ src, ushort16* __restrict__ dst) {
    int i = blockIdx.x * 256 + threadIdx.x;
    float4 v = *(const float4*)(src + (size_t)i * 4);
    uint2 pk;
    pk.x = pk2(v.x, v.y);
    pk.y = pk2(v.z, v.w);
    *(uint2*)(dst + (size_t)i * 4) = pk;
}

// ---------------- bf16 MFMA GEMM: C[M,Nc] = A[M,K] @ W[Nc,K]^T (+res, f32 out) -------
__global__ __launch_bounds__(256) void gemmb_k(const ushort16* __restrict__ A,
                                               const ushort16* __restrict__ W,
                                               const float* __restrict__ res,
                                               float* __restrict__ C,
                                               int M, int Nc, int K) {
    __shared__ __align__(16) short As[64 * 40];
    __shared__ __align__(16) short Ws[64 * 40];
    int tid = threadIdx.x;
    int l = tid & 63, wid = tid >> 6;
    int wm = wid & 1, wn = wid >> 1;
    int row0 = blockIdx.y * 64, col0 = blockIdx.x * 64;
    int r = tid >> 2, kseg = (tid & 3) * 8;
    f32x4 acc[2][2] = {};
    for (int k0 = 0; k0 < K; k0 += 32) {
        *(uint4*)&As[r * 40 + kseg] = *(const uint4*)(A + (size_t)(row0 + r) * K + k0 + kseg);
        *(uint4*)&Ws[r * 40 + kseg] = *(const uint4*)(W + (size_t)(col0 + r) * K + k0 + kseg);
        __syncthreads();
        bf16x8 aF[2], bF[2];
        #pragma unroll
        for (int am = 0; am < 2; ++am)
            aF[am] = *(const bf16x8*)&As[(wm * 32 + am * 16 + (l & 15)) * 40 + (l >> 4) * 8];
        #pragma unroll
        for (int bn = 0; bn < 2; ++bn)
            bF[bn] = *(const bf16x8*)&Ws[(wn * 32 + bn * 16 + (l & 15)) * 40 + (l >> 4) * 8];
        #pragma unroll
        for (int am = 0; am < 2; ++am)
            #pragma unroll
            for (int bn = 0; bn < 2; ++bn)
                acc[am][bn] = __builtin_amdgcn_mfma_f32_16x16x32_bf16(aF[am], bF[bn], acc[am][bn], 0, 0, 0);
        __syncthreads();
    }
    #pragma unroll
    for (int am = 0; am < 2; ++am)
        #pragma unroll
        for (int bn = 0; bn < 2; ++bn) {
            int cc = col0 + wn * 32 + bn * 16 + (l & 15);
            #pragma unroll
            for (int reg = 0; reg < 4; ++reg) {
                int rr = row0 + wm * 32 + am * 16 + (l >> 4) * 4 + reg;
                float v = acc[am][bn][reg];
                if (res) v += res[(size_t)rr * Nc + cc];
                C[(size_t)rr * Nc + cc] = v;
            }
        }
}

// ---------------- cast xz[:, :DI] -> xpb (bf16, with 3-row zero halo per batch) -------
__global__ void cast_k(const float* __restrict__ xz, ushort16* __restrict__ xpb) {
    int i = blockIdx.x * 256 + threadIdx.x;
    int row = i >> 6;
    int off = (i & 63) * 8;
    int b = row >> 9, t = row & (S - 1);
    float4 v0 = *(const float4*)(xz + (size_t)row * (2 * DI) + off);
    float4 v1 = *(const float4*)(xz + (size_t)row * (2 * DI) + off + 4);
    uint4 pk;
    pk.x = pk2(v0.x, v0.y);
    pk.y = pk2(v0.z, v0.w);
    pk.z = pk2(v1.x, v1.y);
    pk.w = pk2(v1.z, v1.w);
    *(uint4*)(xpb + ((size_t)(b * (S + 3) + 3 + t)) * DI + off) = pk;
}

// ---------------- Causal conv via bf16 MFMA + bias + silu ----------------
__global__ __launch_bounds__(256) void convm_k(const ushort16* __restrict__ xpb,
                                               const float* __restrict__ conv_w,
                                               const float* __restrict__ conv_b,
                                               float* __restrict__ x_act) {
    __shared__ __align__(16) short AxS[35 * 40];
    __shared__ __align__(16) short WbS[4 * 32 * 40];
    int tid = threadIdx.x;
    int l = tid & 63, wid = tid >> 6;
    int wm = wid & 1, wn = wid >> 1;
    int o0 = blockIdx.x * 32;
    int mt = blockIdx.y;
    int b = mt >> 4, tl0 = (mt & 15) * 32;
    f32x4 acc = {0.f, 0.f, 0.f, 0.f};

    for (int k0 = 0; k0 < DI; k0 += 32) {
        if (tid < 140) {
            int rr = tid >> 2, seg = tid & 3;
            uint4 v = *(const uint4*)(xpb + ((size_t)(b * (S + 3) + tl0 + rr)) * DI + k0 + seg * 8);
            *(uint4*)&AxS[rr * 40 + seg * 8] = v;
        }
        #pragma unroll
        for (int it = 0; it < 4; ++it) {
            int p = it * 256 + tid;
            int o = p >> 5, i = p & 31;
            float4 w4 = *(const float4*)(conv_w + ((size_t)(o0 + o) * DI + (k0 + i)) * 4);
            WbS[(0 * 32 + o) * 40 + i] = (short)f2bf(w4.x);
            WbS[(1 * 32 + o) * 40 + i] = (short)f2bf(w4.y);
            WbS[(2 * 32 + o) * 40 + i] = (short)f2bf(w4.z);
            WbS[(3 * 32 + o) * 40 + i] = (short)f2bf(w4.w);
        }
        __syncthreads();
        #pragma unroll
        for (int k = 0; k < 4; ++k) {
            bf16x8 aF = *(const bf16x8*)&AxS[(wm * 16 + (l & 15) + k) * 40 + (l >> 4) * 8];
            bf16x8 bF = *(const bf16x8*)&WbS[(k * 32 + wn * 16 + (l & 15)) * 40 + (l >> 4) * 8];
            acc = __builtin_amdgcn_mfma_f32_16x16x32_bf16(aF, bF, acc, 0, 0, 0);
        }
        __syncthreads();
    }
    int oc = o0 + wn * 16 + (l & 15);
    float bia = conv_b[oc];
    #pragma unroll
    for (int reg = 0; reg < 4; ++reg) {
        int m = wm * 16 + (l >> 4) * 4 + reg;
        float v = acc[reg] + bia;
        x_act[((size_t)(b * S + tl0 + m)) * DI + oc] = v / (1.0f + __expf(-v));
    }
}

// ---------------- ssm = x_act @ W_xp^T (33 outputs) ----------------
__global__ void ssm_k(const float* __restrict__ x_act, const float* __restrict__ W_xp,
                      float* __restrict__ dt_raw, float* __restrict__ Bm, float* __restrict__ Cm) {
    int row = blockIdx.x * 4 + (threadIdx.x >> 6);
    int lane = threadIdx.x & 63;
    const float* xr = x_act + (size_t)row * DI + lane * 8;
    float4 v0 = *(const float4*)xr;
    float4 v1 = *(const float4*)(xr + 4);
    for (int j = 0; j < 2 * N + 1; ++j) {
        const float* wr = W_xp + (size_t)j * DI + lane * 8;
        float4 w0 = *(const float4*)wr;
        float4 w1 = *(const float4*)(wr + 4);
        float acc = v0.x * w0.x + v0.y * w0.y + v0.z * w0.z + v0.w * w0.w
                  + v1.x * w1.x + v1.y * w1.y + v1.z * w1.z + v1.w * w1.w;
        for (int m = 1; m < 64; m <<= 1) acc += __shfl_xor(acc, m);
        if (lane == 0) {
            if (j == 0)           dt_raw[row] = acc;
            else if (j < 1 + N)   Bm[(size_t)row * N + (j - 1)] = acc;
            else                  Cm[(size_t)row * N + (j - 1 - N)] = acc;
        }
    }
}

// ---------------- rdeg = 1/max(sum_{s<t} adj,1); flag[t] ----------------
__global__ void deg_k(const float* __restrict__ adj, float* __restrict__ rdeg, int* __restrict__ flagI) {
    int t = blockIdx.x & (S - 1), b = blockIdx.x >> 9;
    int lane = threadIdx.x;
    const float* row = adj + ((size_t)(b * S + t)) * S;
    float s = 0.0f; bool anyp = false;
    for (int i = lane; i < t; i += 64) { float v = row[i]; s += v; anyp |= (v > 0.0f); }
    for (int m = 1; m < 64; m <<= 1) s += __shfl_xor(s, m);
    bool any = __any(anyp);
    if (lane == 0) {
        rdeg[b * S + t] = 1.0f / fmaxf(s, 1.0f);
        if (t > 0 && any) atomicOr(flagI + t, 1);
    }
}

// ---------------- E = exp(-softplus(dt)), zs = silu(z) ----------------
__global__ void ez_k(const float* __restrict__ dt_raw, const float* __restrict__ W_dt,
                     const float* __restrict__ b_dt, const float* __restrict__ xz,
                     float* __restrict__ E, float* __restrict__ zs) {
    int i = blockIdx.x * 256 + threadIdx.x;
    int d = i & (DI - 1);
    int row = i >> 9;
    float vv = dt_raw[row] * W_dt[d] + b_dt[d];
    E[i] = 1.0f / (1.0f + __expf(vv));
    float z = xz[(size_t)row * (2 * DI) + DI + d];
    zs[i] = z / (1.0f + __expf(-z));
}

// ================= dual-chunk fused kernel (128 threads, 384 blocks) =================
// Per launch lc: scan chunks A=2lc, B=2lc+1. G slot layout in Gall (bf16,
// [parity][slot][b][dn][j32]): slot 0/1 = Gold(tgt0/1) from gpast; slots 2..5 =
// tails (src,tgt) from previous launch's scan blocks (src*2+tgt).
// blocks [0,128): scan role.  blocks [128,384): gpast role (tgt,b,tile).
#define SCAN32(RO, ADJT, GSUM)                                              \
    _Pragma("unroll")                                                       \
    for (int j = 0; j < CHUNK; ++j) {                                       \
        float e  = eL [((RO) + j) * 8 + grp];                               \
        float xa = xaL[((RO) + j) * 8 + grp];                               \
        float Bn = BnL[((RO) + j) * 16 + n];                                \
        h = h * e + xa * Bn;                                                \
        float g0 = GSUM[j], g1 = 0.f, g2 = 0.f, g3 = 0.f;                   \
        const float* ar = (ADJT) + j * 36;                                  \
        int sp = 0;                                                         \
        _Pragma("unroll")                                                   \
        for (; sp + 4 <= j; sp += 4) {                                      \
            float4 av = *(const float4*)(ar + sp);                          \
            g0 += av.x * hreg[sp];     g1 += av.y * hreg[sp + 1];           \
            g2 += av.z * hreg[sp + 2]; g3 += av.w * hreg[sp + 3];           \
        }                                                                   \
        _Pragma("unroll")                                                   \
        for (; sp < j; ++sp) g0 += ar[sp] * hreg[sp];                       \
        float gr = (g0 + g1) + (g2 + g3);                                   \
        gx[tid] = gr;                                                       \
        __threadfence_block();                                              \
        float4 gA = *(const float4*)&gx[grp16];                             \
        float4 gB = *(const float4*)&gx[grp16 + 4];                         \
        float4 gC = *(const float4*)&gx[grp16 + 8];                         \
        float4 gD = *(const float4*)&gx[grp16 + 12];                        \
        float m0 = gA.x*wr[0]+gA.y*wr[1]+gA.z*wr[2]+gA.w*wr[3];             \
        float m1 = gB.x*wr[4]+gB.y*wr[5]+gB.z*wr[6]+gB.w*wr[7];             \
        float m2 = gC.x*wr[8]+gC.y*wr[9]+gC.z*wr[10]+gC.w*wr[11];           \
        float m3 = gD.x*wr[12]+gD.y*wr[13]+gD.z*wr[14]+gD.w*wr[15];         \
        float acc = fmaf(rdegL[(RO) + j], (m0+m1)+(m2+m3), brn);            \
        if (flL[(RO) + j]) h += 0.1f * acc / (1.0f + __expf(-acc));         \
        hreg[j] = h;                                                        \
    }

#define PRESUM(GSUM, PTR) {                                                 \
    const ushort16* _p = (PTR);                                             \
    _Pragma("unroll")                                                       \
    for (int qi = 0; qi < 4; ++qi) {                                        \
        uint4 q = *(const uint4*)(_p + qi * 8);                             \
        GSUM[qi*8+0] += bflo(q.x); GSUM[qi*8+1] += bfhi(q.x);               \
        GSUM[qi*8+2] += bflo(q.y); GSUM[qi*8+3] += bfhi(q.y);               \
        GSUM[qi*8+4] += bflo(q.z); GSUM[qi*8+5] += bfhi(q.z);               \
        GSUM[qi*8+6] += bflo(q.w); GSUM[qi*8+7] += bfhi(q.w);               \
    } }

__global__ __launch_bounds__(128) void chunk2_k(const float* __restrict__ adj,
                                                const float* __restrict__ x_act,
                                                const float* __restrict__ E,
                                                const float* __restrict__ Bm,
                                                const float* __restrict__ rdeg,
                                                const int* __restrict__ flagI,
                                                const float* __restrict__ Wr,
                                                const float* __restrict__ br,
                                                ushort16* __restrict__ Gall,
                                                ushort16* __restrict__ histT,
                                                float* __restrict__ hlast, int lc) {
    __shared__ __align__(16) char smem[56320];
    int tid = threadIdx.x;
    int cbA = 2 * lc * CHUNK;
    int cbB = cbA + CHUNK;
    const size_t SLOT = (size_t)B * DN * 32;
    int rp = lc & 1, wp = (lc + 1) & 1;

    if (blockIdx.x < 128) {
        // ---------------- scan role (2 chunks) ----------------
        float* adjA  = (float*)smem;                    // 32*36 f32
        float* adjB  = (float*)(smem + 4608);
        short* AsM   = (short*)(smem + 9216);           // mid tile (A->B) 32*40
        short* AsT   = (short*)(smem + 11776);          // 4 tail tiles 32*40 each
        float* eL    = (float*)(smem + 22016);          // [64][8]
        float* xaL   = (float*)(smem + 24064);
        float* BnL   = (float*)(smem + 26112);          // [64][16]
        float* rdegL = (float*)(smem + 30208);          // [64]
        int*   flL   = (int*)  (smem + 30464);          // [64]
        float* gx    = (float*)(smem + 30720);          // [128]
        short* hTA   = (short*)(smem + 31232);          // [4][128][8]
        float* Gmid  = (float*)(smem + 39424);          // [32][129] f32 (union w/ hTB)
        short* hTB   = (short*)(smem + 39424);          // [4][128][8]

        int b = blockIdx.x >> 6;
        int d0 = (blockIdx.x & 63) << 3;
        int n = tid & 15, grp = tid >> 4;               // grp 0..7
        int grp16 = grp * 16;
        int d = d0 + grp;
        int dn = d * N + n;
        int dnbase = (blockIdx.x & 63) << 7;

        // ---- stage ----
        {
            int j = tid >> 2, s8 = (tid & 3) * 8;
            {
                const float* ar0 = adj + ((size_t)(b * S + cbA + j)) * S + cbA + s8;
                float4 a0 = *(const float4*)ar0, a1 = *(const float4*)(ar0 + 4);
                float* dp = adjA + j * 36 + s8;
                dp[0]=a0.x; dp[1]=a0.y; dp[2]=a0.z; dp[3]=a0.w;
                dp[4]=a1.x; dp[5]=a1.y; dp[6]=a1.z; dp[7]=a1.w;
            }
            {
                const float* ar0 = adj + ((size_t)(b * S + cbB + j)) * S + cbB + s8;
                float4 a0 = *(const float4*)ar0, a1 = *(const float4*)(ar0 + 4);
                float* dp = adjB + j * 36 + s8;
                dp[0]=a0.x; dp[1]=a0.y; dp[2]=a0.z; dp[3]=a0.w;
                dp[4]=a1.x; dp[5]=a1.y; dp[6]=a1.z; dp[7]=a1.w;
            }
            {   // mid tile: rows of B vs cols of A
                const float* ar0 = adj + ((size_t)(b * S + cbB + j)) * S + cbA + s8;
                float4 a0 = *(const float4*)ar0, a1 = *(const float4*)(ar0 + 4);
                uint4 q;
                q.x = pk2(a0.x, a0.y); q.y = pk2(a0.z, a0.w);
                q.z = pk2(a1.x, a1.y); q.w = pk2(a1.z, a1.w);
                *(uint4*)&AsM[j * 40 + s8] = q;
            }
            if (lc < NL - 1) {   // 4 tail tiles: rows of (cbA+64+32*tgt) vs cols of (cbA+32*src)
                #pragma unroll
                for (int src = 0; src < 2; ++src)
                    #pragma unroll
                    for (int tgt = 0; tgt < 2; ++tgt) {
                        const float* ar0 = adj + ((size_t)(b * S + cbA + 64 + 32 * tgt + j)) * S
                                         + cbA + 32 * src + s8;
                        float4 a0 = *(const float4*)ar0, a1 = *(const float4*)(ar0 + 4);
                        uint4 q;
                        q.x = pk2(a0.x, a0.y); q.y = pk2(a0.z, a0.w);
                        q.z = pk2(a1.x, a1.y); q.w = pk2(a1.z, a1.w);
                        *(uint4*)&AsT[(src * 2 + tgt) * (32 * 40) + j * 40 + s8] = q;
                    }
            }
            int jr = tid >> 1, dd = (tid & 1) * 4;
            float4 ev = *(const float4*)(E     + ((size_t)(b * S + cbA + jr)) * DI + d0 + dd);
            float4 xv = *(const float4*)(x_act + ((size_t)(b * S + cbA + jr)) * DI + d0 + dd);
            eL [jr * 8 + dd] = ev.x; eL [jr * 8 + dd + 1] = ev.y;
            eL [jr * 8 + dd + 2] = ev.z; eL [jr * 8 + dd + 3] = ev.w;
            xaL[jr * 8 + dd] = xv.x; xaL[jr * 8 + dd + 1] = xv.y;
            xaL[jr * 8 + dd + 2] = xv.z; xaL[jr * 8 + dd + 3] = xv.w;
            int nn = (tid & 1) * 8;
            float4 b0 = *(const float4*)(Bm + ((size_t)(b * S + cbA + jr)) * N + nn);
            float4 b1 = *(const float4*)(Bm + ((size_t)(b * S + cbA + jr)) * N + nn + 4);
            BnL[jr * 16 + nn] = b0.x; BnL[jr * 16 + nn + 1] = b0.y;
            BnL[jr * 16 + nn + 2] = b0.z; BnL[jr * 16 + nn + 3] = b0.w;
            BnL[jr * 16 + nn + 4] = b1.x; BnL[jr * 16 + nn + 5] = b1.y;
            BnL[jr * 16 + nn + 6] = b1.z; BnL[jr * 16 + nn + 7] = b1.w;
            if (tid < 64) {
                rdegL[tid] = rdeg[b * S + cbA + tid];
                flL[tid]   = flagI[cbA + tid];
            }
        }

        // ---- presum G for both chunks ----
        float gsA[CHUNK], gsB[CHUNK];
        #pragma unroll
        for (int j = 0; j < CHUNK; ++j) { gsA[j] = 0.f; gsB[j] = 0.f; }
        {
            size_t tb = ((size_t)b * DN + dn) * 32;
            if (lc >= 2) {
                PRESUM(gsA, Gall + ((size_t)rp * 6 + 0) * SLOT + tb);
                PRESUM(gsB, Gall + ((size_t)rp * 6 + 1) * SLOT + tb);
            }
            if (lc >= 1) {
                PRESUM(gsA, Gall + ((size_t)rp * 6 + 2) * SLOT + tb);   // src0->tgt0
                PRESUM(gsA, Gall + ((size_t)rp * 6 + 4) * SLOT + tb);   // src1->tgt0
                PRESUM(gsB, Gall + ((size_t)rp * 6 + 3) * SLOT + tb);   // src0->tgt1
                PRESUM(gsB, Gall + ((size_t)rp * 6 + 5) * SLOT + tb);   // src1->tgt1
            }
        }

        float wr[16];
        #pragma unroll
        for (int m = 0; m < 16; ++m) wr[m] = Wr[n * 16 + m];
        float brn = br[n];
        float h = (lc == 0) ? 0.0f : hlast[b * DN + dn];
        __syncthreads();

        float hreg[CHUNK];
        // ======== scan chunk A ========
        SCAN32(0, adjA, gsA)

        // histT(A) + hTA
        {
            ushort16* ht = histT + ((size_t)b * DN + dn) * S + cbA;
            #pragma unroll
            for (int qi = 0; qi < 4; ++qi) {
                uint4 q;
                q.x = pk2(hreg[qi*8+0], hreg[qi*8+1]);
                q.y = pk2(hreg[qi*8+2], hreg[qi*8+3]);
                q.z = pk2(hreg[qi*8+4], hreg[qi*8+5]);
                q.w = pk2(hreg[qi*8+6], hreg[qi*8+7]);
                *(uint4*)(ht + qi * 8) = q;
                *(uint4*)&hTA[qi * 1024 + tid * 8] = q;
            }
        }
        __syncthreads();
        // ======== mid MFMA: Gmid[j][dn] = adj(B rows, A cols) x histA ========
        {
            int w = tid >> 6, l = tid & 63;
            bf16x8 aF0 = *(const bf16x8*)&AsM[(l & 15) * 40 + (l >> 4) * 8];
            bf16x8 aF1 = *(const bf16x8*)&AsM[(16 + (l & 15)) * 40 + (l >> 4) * 8];
            #pragma unroll
            for (int dblk = 0; dblk < 4; ++dblk) {
                int col = w * 64 + dblk * 16 + (l & 15);
                bf16x8 bF = *(const bf16x8*)&hTA[(l >> 4) * 1024 + col * 8];
                f32x4 a0v = {0.f,0.f,0.f,0.f}, a1v = {0.f,0.f,0.f,0.f};
                a0v = __builtin_amdgcn_mfma_f32_16x16x32_bf16(aF0, bF, a0v, 0, 0, 0);
                a1v = __builtin_amdgcn_mfma_f32_16x16x32_bf16(aF1, bF, a1v, 0, 0, 0);
                int jb0 = (l >> 4) * 4;
                #pragma unroll
                for (int reg = 0; reg < 4; ++reg) {
                    Gmid[(jb0 + reg) * 129 + col]      = a0v[reg];
                    Gmid[(16 + jb0 + reg) * 129 + col] = a1v[reg];
                }
            }
        }
        __syncthreads();
        #pragma unroll
        for (int j = 0; j < CHUNK; ++j) gsB[j] += Gmid[j * 129 + tid];
        __syncthreads();    // Gmid reads done before hTB overlay write

        // ======== scan chunk B ========
        SCAN32(32, adjB, gsB)
        hlast[b * DN + dn] = h;

        // histT(B) + hTB
        {
            ushort16* ht = histT + ((size_t)b * DN + dn) * S + cbB;
            #pragma unroll
            for (int qi = 0; qi < 4; ++qi) {
                uint4 q;
                q.x = pk2(hreg[qi*8+0], hreg[qi*8+1]);
                q.y = pk2(hreg[qi*8+2], hreg[qi*8+3]);
                q.z = pk2(hreg[qi*8+4], hreg[qi*8+5]);
                q.w = pk2(hreg[qi*8+6], hreg[qi*8+7]);
                *(uint4*)(ht + qi * 8) = q;
                *(uint4*)&hTB[qi * 1024 + tid * 8] = q;
            }
        }
        // ======== tails: chunks {A,B} -> targets {2lc+2, 2lc+3} via MFMA ========
        if (lc < NL - 1) {
            __syncthreads();
            int w = tid >> 6, l = tid & 63;
            int jb0 = (l >> 4) * 4;
            #pragma unroll
            for (int src = 0; src < 2; ++src) {
                const short* hTs = src ? hTB : hTA;
                #pragma unroll
                for (int tgt = 0; tgt < 2; ++tgt) {
                    const short* At = AsT + (src * 2 + tgt) * (32 * 40);
                    bf16x8 aF0 = *(const bf16x8*)&At[(l & 15) * 40 + (l >> 4) * 8];
                    bf16x8 aF1 = *(const bf16x8*)&At[(16 + (l & 15)) * 40 + (l >> 4) * 8];
                    ushort16* gw = Gall + ((size_t)wp * 6 + (2 + src * 2 + tgt)) * SLOT;
                    #pragma unroll
                    for (int dblk = 0; dblk < 4; ++dblk) {
                        int col = w * 64 + dblk * 16 + (l & 15);
                        bf16x8 bF = *(const bf16x8*)&hTs[(l >> 4) * 1024 + col * 8];
                        f32x4 a0v = {0.f,0.f,0.f,0.f}, a1v = {0.f,0.f,0.f,0.f};
                        a0v = __builtin_amdgcn_mfma_f32_16x16x32_bf16(aF0, bF, a0v, 0, 0, 0);
                        a1v = __builtin_amdgcn_mfma_f32_16x16x32_bf16(aF1, bF, a1v, 0, 0, 0);
                        int dng = dnbase + col;
                        uint2 o0, o1;
                        o0.x = pk2(a0v[0], a0v[1]); o0.y = pk2(a0v[2], a0v[3]);
                        o1.x = pk2(a1v[0], a1v[1]); o1.y = pk2(a1v[2], a1v[3]);
                        *(uint2*)(gw + ((size_t)b * DN + dng) * 32 + jb0) = o0;
                        *(uint2*)(gw + ((size_t)b * DN + dng) * 32 + 16 + jb0) = o1;
                    }
                }
            }
        }
    } else {
        // ---------------- gpast role: Gold(tgt) over chunks 0..2lc-1 ----------------
        if (lc == 0 || lc >= NL - 1) return;
        short* As2 = (short*)smem;                 // 32*40
        short* Ws2 = (short*)(smem + 2560);        // 128*40
        int idx = blockIdx.x - 128;                // 0..255
        int tile = idx & 63;
        int b = (idx >> 6) & 1;
        int tgt = idx >> 7;
        int tc = 2 * lc + 2 + tgt;                 // target chunk index
        int dn0 = tile * 128;
        int w = tid >> 6, l = tid & 63;

        f32x4 acc[8] = {};
        for (int ks = 0; ks < 2 * lc; ++ks) {
            {
                int j = tid >> 2, s8 = (tid & 3) * 8;
                const float* arow = adj + ((size_t)(b * S + tc * CHUNK + j)) * S + ks * CHUNK + s8;
                float4 a0 = *(const float4*)arow;
                float4 a1 = *(const float4*)(arow + 4);
                uint4 q;
                q.x = pk2(a0.x, a0.y); q.y = pk2(a0.z, a0.w);
                q.z = pk2(a1.x, a1.y); q.w = pk2(a1.z, a1.w);
                *(uint4*)&As2[j * 40 + s8] = q;
                #pragma unroll
                for (int seg = 0; seg < 4; ++seg)
                    *(uint4*)&Ws2[tid * 40 + seg * 8] =
                        *(const uint4*)(histT + ((size_t)b * DN + dn0 + tid) * S + ks * CHUNK + seg * 8);
            }
            __syncthreads();
            bf16x8 aF = *(const bf16x8*)&As2[(w * 16 + (l & 15)) * 40 + (l >> 4) * 8];
            #pragma unroll
            for (int dblk = 0; dblk < 8; ++dblk) {
                bf16x8 bF = *(const bf16x8*)&Ws2[(dblk * 16 + (l & 15)) * 40 + (l >> 4) * 8];
                acc[dblk] = __builtin_amdgcn_mfma_f32_16x16x32_bf16(aF, bF, acc[dblk], 0, 0, 0);
            }
            __syncthreads();
        }
        int jb = w * 16 + (l >> 4) * 4;
        ushort16* gbase = Gall + ((size_t)wp * 6 + tgt) * SLOT;
        #pragma unroll
        for (int dblk = 0; dblk < 8; ++dblk) {
            int dnc = dn0 + dblk * 16 + (l & 15);
            uint2 o;
            o.x = pk2(acc[dblk][0], acc[dblk][1]);
            o.y = pk2(acc[dblk][2], acc[dblk][3]);
            *(uint2*)(gbase + ((size_t)b * DN + dnc) * 32 + jb) = o;
        }
    }
}

// ---------------- y_k: y[b,t,d] = (sum_n histT[b][dn][t]*Cm[b,t,n]) * zs[b,t,d] -------
__global__ __launch_bounds__(256) void y_k(const ushort16* __restrict__ histT,
                                           const float* __restrict__ Cm,
                                           const float* __restrict__ zs,
                                           ushort16* __restrict__ yzb) {
    __shared__ float CmL[S * 17];
    int b = blockIdx.x >> 9;
    int d = blockIdx.x & (DI - 1);
    int tid = threadIdx.x;
    #pragma unroll
    for (int q = 0; q < 8; ++q) {
        int l0 = q * 1024 + tid * 4;
        int t = l0 >> 4, n0 = l0 & 15;
        float4 v = *(const float4*)(Cm + (size_t)b * S * N + l0);
        CmL[t * 17 + n0]     = v.x;
        CmL[t * 17 + n0 + 1] = v.y;
        CmL[t * 17 + n0 + 2] = v.z;
        CmL[t * 17 + n0 + 3] = v.w;
    }
    __syncthreads();
    const ushort16* hbase = histT + ((size_t)b * DN + d * N) * S;
    #pragma unroll
    for (int pass = 0; pass < 2; ++pass) {
        int t = pass * 256 + tid;
        float a0 = 0.f, a1 = 0.f, a2 = 0.f, a3 = 0.f;
        #pragma unroll
        for (int n = 0; n < 16; n += 4) {
            a0 += bf2f(hbase[(size_t)n * S + t])       * CmL[t * 17 + n];
            a1 += bf2f(hbase[(size_t)(n + 1) * S + t]) * CmL[t * 17 + n + 1];
            a2 += bf2f(hbase[(size_t)(n + 2) * S + t]) * CmL[t * 17 + n + 2];
            a3 += bf2f(hbase[(size_t)(n + 3) * S + t]) * CmL[t * 17 + n + 3];
        }
        float acc = (a0 + a1) + (a2 + a3);
        float zv = zs[((size_t)(b * S + t)) * DI + d];
        yzb[((size_t)(b * S + t)) * DI + d] = f2bf(acc * zv);
    }
}

// ---------------- launch ----------------
extern "C" void kernel_launch(void* const* d_in, const int* in_sizes, int n_in,
                              void* d_out, int out_size, void* d_ws, size_t ws_size,
                              hipStream_t stream) {
    const float* x      = (const float*)d_in[0];
    const float* adj    = (const float*)d_in[1];
    const float* ln_w   = (const float*)d_in[2];
    const float* ln_b   = (const float*)d_in[3];
    const float* W_in   = (const float*)d_in[4];
    const float* conv_w = (const float*)d_in[5];
    const float* conv_b = (const float*)d_in[6];
    const float* W_xp   = (const float*)d_in[7];
    const float* W_dt   = (const float*)d_in[8];
    const float* b_dt   = (const float*)d_in[9];
    const float* Wr     = (const float*)d_in[10];
    const float* br     = (const float*)d_in[11];
    const float* W_out  = (const float*)d_in[12];
    float* out = (float*)d_out;

    float* ws = (float*)d_ws;
    size_t off = 0;
    float* xz     = ws + off; off += (size_t)B * S * 2 * DI;
    float* x_act  = ws + off; off += (size_t)B * S * DI;
    float* dt_raw = ws + off; off += (size_t)B * S;
    float* Bmb    = ws + off; off += (size_t)B * S * N;
    float* Cmb    = ws + off; off += (size_t)B * S * N;
    float* rdegp  = ws + off; off += (size_t)B * S;
    int*   flagI  = (int*)(ws + off); off += S;
    float* Ebuf   = ws + off; off += (size_t)B * S * DI;
    float* zsbuf  = ws + off; off += (size_t)B * S * DI;
    float* hlast  = ws + off; off += (size_t)B * DN;
    ushort16* xnb    = (ushort16*)(ws + off); off += (size_t)B * S * D / 2;
    ushort16* yzb    = (ushort16*)(ws + off); off += (size_t)B * S * DI / 2;
    ushort16* histT  = (ushort16*)(ws + off); off += (size_t)B * DN * S / 2;
    ushort16* Gall   = (ushort16*)(ws + off); off += (size_t)2 * 6 * B * DN * 32 / 2;
    ushort16* xpb    = (ushort16*)(ws + off); off += (size_t)B * (S + 3) * DI / 2;
    ushort16* W_inb  = (ushort16*)(ws + off); off += (size_t)2 * DI * D / 2;
    ushort16* W_outb = (ushort16*)(ws + off); off += (size_t)D * DI / 2;

    hipMemsetAsync(flagI, 0, S * sizeof(int), stream);
    hipMemsetAsync(xpb, 0, (size_t)B * (S + 3) * DI * 2, stream);

    ln_k<<<B * S, 64, 0, stream>>>(x, ln_w, ln_b, xnb);
    wcast_k<<<(2 * DI * D) / 1024, 256, 0, stream>>>(W_in, W_inb);
    wcast_k<<<(D * DI) / 1024, 256, 0, stream>>>(W_out, W_outb);
    gemmb_k<<<dim3(2 * DI / 64, B * S / 64), 256, 0, stream>>>(xnb, W_inb, nullptr, xz, B * S, 2 * DI, D);
    cast_k<<<B * S * DI / (256 * 8), 256, 0, stream>>>(xz, xpb);
    convm_k<<<dim3(DI / 32, B * S / 32), 256, 0, stream>>>(xpb, conv_w, conv_b, x_act);
    ssm_k<<<B * S / 4, 256, 0, stream>>>(x_act, W_xp, dt_raw, Bmb, Cmb);
    deg_k<<<B * S, 64, 0, stream>>>(adj, rdegp, flagI);
    ez_k<<<B * S * DI / 256, 256, 0, stream>>>(dt_raw, W_dt, b_dt, xz, Ebuf, zsbuf);

    for (int lc = 0; lc < NL; ++lc)
        chunk2_k<<<384, 128, 0, stream>>>(adj, x_act, Ebuf, Bmb, rdegp, flagI,
                                          Wr, br, Gall, histT, hlast, lc);

    y_k<<<B * DI, 256, 0, stream>>>(histT, Cmb, zsbuf, yzb);

    gemmb_k<<<dim3(D / 64, B * S / 64), 256, 0, stream>>>(yzb, W_outb, x, out, B * S, D, DI);
}

// Round 12
// 277.828 us; speedup vs baseline: 4.1961x; 1.1351x over previous
//
#include <hip/hip_runtime.h>
#include <math.h>

// Problem constants
static constexpr int B  = 2;
static constexpr int S  = 512;
static constexpr int D  = 256;
static constexpr int N  = 16;
static constexpr int DI = 512;
static constexpr int CHUNK = 32;
static constexpr int NCHUNK = S / CHUNK;   // 16
static constexpr int NL = NCHUNK / 2;      // 8 launches, 2 chunks each
static constexpr int DN = DI * N;          // 8192

typedef unsigned int uint32;
typedef unsigned short ushort16;
using bf16x8 = __attribute__((ext_vector_type(8))) short;
using f32x4  = __attribute__((ext_vector_type(4))) float;

__device__ __forceinline__ ushort16 f2bf(float f) {
    uint32 u = __float_as_uint(f);
    u = (u + 0x7fffu + ((u >> 16) & 1u)) >> 16;   // RNE
    return (ushort16)u;
}
__device__ __forceinline__ float bflo(uint32 u) { return __uint_as_float(u << 16); }
__device__ __forceinline__ float bfhi(uint32 u) { return __uint_as_float(u & 0xffff0000u); }
__device__ __forceinline__ float bf2f(ushort16 u) { return __uint_as_float(((uint32)u) << 16); }
__device__ __forceinline__ uint32 pk2(float a, float b) {
    return (uint32)(ushort16)f2bf(a) | ((uint32)(ushort16)f2bf(b) << 16);
}
// DPP row-rotate within 16-lane rows (VALU pipe, no LDS)
template<int K>
__device__ __forceinline__ float rork(float x) {
    return __uint_as_float((uint32)__builtin_amdgcn_mov_dpp(
        (int)__float_as_uint(x), 0x120 + K, 0xf, 0xf, false));
}

// ---------------- LayerNorm: one wave per row, bf16 output ----------------
__global__ void ln_k(const float* __restrict__ x, const float* __restrict__ w,
                     const float* __restrict__ bias, ushort16* __restrict__ xnb) {
    int row = blockIdx.x;
    int lane = threadIdx.x;
    float4 v = *(const float4*)(x + row * D + lane * 4);
    float s = v.x + v.y + v.z + v.w;
    float q = v.x * v.x + v.y * v.y + v.z * v.z + v.w * v.w;
    for (int m = 1; m < 64; m <<= 1) { s += __shfl_xor(s, m); q += __shfl_xor(q, m); }
    float mu  = s * (1.0f / D);
    float var = q * (1.0f / D) - mu * mu;
    float rs  = rsqrtf(var + 1e-5f);
    float4 wv = *(const float4*)(w + lane * 4);
    float4 bv = *(const float4*)(bias + lane * 4);
    float4 o;
    o.x = (v.x - mu) * rs * wv.x + bv.x;
    o.y = (v.y - mu) * rs * wv.y + bv.y;
    o.z = (v.z - mu) * rs * wv.z + bv.z;
    o.w = (v.w - mu) * rs * wv.w + bv.w;
    uint2 pk;
    pk.x = pk2(o.x, o.y);
    pk.y = pk2(o.z, o.w);
    *(uint2*)(xnb + row * D + lane * 4) = pk;
}

// ------- bf16 MFMA GEMM, W in f32 (converted during staging) -------
// MODE 0: C[M,Nc] = A@W^T (+res), f32 out.
// MODE 1: first GEMM: cols<DI -> xpb bf16 (3-row halo layout); cols>=DI -> zs=silu.
template<int MODE>
__global__ __launch_bounds__(256) void gemmb_k(const ushort16* __restrict__ A,
                                               const float* __restrict__ W,
                                               const float* __restrict__ res,
                                               float* __restrict__ C,
                                               ushort16* __restrict__ xpb,
                                               float* __restrict__ zs,
                                               int M, int Nc, int K) {
    __shared__ __align__(16) short As[64 * 40];
    __shared__ __align__(16) short Ws[64 * 40];
    int tid = threadIdx.x;
    int l = tid & 63, wid = tid >> 6;
    int wm = wid & 1, wn = wid >> 1;
    int row0 = blockIdx.y * 64, col0 = blockIdx.x * 64;
    int r = tid >> 2, kseg = (tid & 3) * 8;
    f32x4 acc[2][2] = {};
    for (int k0 = 0; k0 < K; k0 += 32) {
        *(uint4*)&As[r * 40 + kseg] = *(const uint4*)(A + (size_t)(row0 + r) * K + k0 + kseg);
        {
            const float* wrow = W + (size_t)(col0 + r) * K + k0 + kseg;
            float4 w0 = *(const float4*)wrow;
            float4 w1 = *(const float4*)(wrow + 4);
            uint4 q;
            q.x = pk2(w0.x, w0.y); q.y = pk2(w0.z, w0.w);
            q.z = pk2(w1.x, w1.y); q.w = pk2(w1.z, w1.w);
            *(uint4*)&Ws[r * 40 + kseg] = q;
        }
        __syncthreads();
        bf16x8 aF[2], bF[2];
        #pragma unroll
        for (int am = 0; am < 2; ++am)
            aF[am] = *(const bf16x8*)&As[(wm * 32 + am * 16 + (l & 15)) * 40 + (l >> 4) * 8];
        #pragma unroll
        for (int bn = 0; bn < 2; ++bn)
            bF[bn] = *(const bf16x8*)&Ws[(wn * 32 + bn * 16 + (l & 15)) * 40 + (l >> 4) * 8];
        #pragma unroll
        for (int am = 0; am < 2; ++am)
            #pragma unroll
            for (int bn = 0; bn < 2; ++bn)
                acc[am][bn] = __builtin_amdgcn_mfma_f32_16x16x32_bf16(aF[am], bF[bn], acc[am][bn], 0, 0, 0);
        __syncthreads();
    }
    #pragma unroll
    for (int am = 0; am < 2; ++am)
        #pragma unroll
        for (int bn = 0; bn < 2; ++bn) {
            int cc = col0 + wn * 32 + bn * 16 + (l & 15);
            #pragma unroll
            for (int reg = 0; reg < 4; ++reg) {
                int rr = row0 + wm * 32 + am * 16 + (l >> 4) * 4 + reg;
                float v = acc[am][bn][reg];
                if (MODE == 0) {
                    if (res) v += res[(size_t)rr * Nc + cc];
                    C[(size_t)rr * Nc + cc] = v;
                } else {
                    int b = rr >> 9, t = rr & (S - 1);
                    if (cc < DI)
                        xpb[((size_t)(b * (S + 3) + 3 + t)) * DI + cc] = f2bf(v);
                    else
                        zs[((size_t)(b * S + t)) * DI + (cc - DI)] = v / (1.0f + __expf(-v));
                }
            }
        }
}

// ---------------- Causal conv via bf16 MFMA + bias + silu ----------------
__global__ __launch_bounds__(256) void convm_k(const ushort16* __restrict__ xpb,
                                               const float* __restrict__ conv_w,
                                               const float* __restrict__ conv_b,
                                               float* __restrict__ x_act) {
    __shared__ __align__(16) short AxS[35 * 40];
    __shared__ __align__(16) short WbS[4 * 32 * 40];
    int tid = threadIdx.x;
    int l = tid & 63, wid = tid >> 6;
    int wm = wid & 1, wn = wid >> 1;
    int o0 = blockIdx.x * 32;
    int mt = blockIdx.y;
    int b = mt >> 4, tl0 = (mt & 15) * 32;
    f32x4 acc = {0.f, 0.f, 0.f, 0.f};

    for (int k0 = 0; k0 < DI; k0 += 32) {
        if (tid < 140) {
            int rr = tid >> 2, seg = tid & 3;
            uint4 v = *(const uint4*)(xpb + ((size_t)(b * (S + 3) + tl0 + rr)) * DI + k0 + seg * 8);
            *(uint4*)&AxS[rr * 40 + seg * 8] = v;
        }
        #pragma unroll
        for (int it = 0; it < 4; ++it) {
            int p = it * 256 + tid;
            int o = p >> 5, i = p & 31;
            float4 w4 = *(const float4*)(conv_w + ((size_t)(o0 + o) * DI + (k0 + i)) * 4);
            WbS[(0 * 32 + o) * 40 + i] = (short)f2bf(w4.x);
            WbS[(1 * 32 + o) * 40 + i] = (short)f2bf(w4.y);
            WbS[(2 * 32 + o) * 40 + i] = (short)f2bf(w4.z);
            WbS[(3 * 32 + o) * 40 + i] = (short)f2bf(w4.w);
        }
        __syncthreads();
        #pragma unroll
        for (int k = 0; k < 4; ++k) {
            bf16x8 aF = *(const bf16x8*)&AxS[(wm * 16 + (l & 15) + k) * 40 + (l >> 4) * 8];
            bf16x8 bF = *(const bf16x8*)&WbS[(k * 32 + wn * 16 + (l & 15)) * 40 + (l >> 4) * 8];
            acc = __builtin_amdgcn_mfma_f32_16x16x32_bf16(aF, bF, acc, 0, 0, 0);
        }
        __syncthreads();
    }
    int oc = o0 + wn * 16 + (l & 15);
    float bia = conv_b[oc];
    #pragma unroll
    for (int reg = 0; reg < 4; ++reg) {
        int m = wm * 16 + (l >> 4) * 4 + reg;
        float v = acc[reg] + bia;
        x_act[((size_t)(b * S + tl0 + m)) * DI + oc] = v / (1.0f + __expf(-v));
    }
}

// ------- ssm (33 outputs) + E epilogue: E = exp(-softplus(dt_raw*W_dt+b_dt)) -------
__global__ void ssmE_k(const float* __restrict__ x_act, const float* __restrict__ W_xp,
                       const float* __restrict__ W_dt, const float* __restrict__ b_dt,
                       float* __restrict__ Bm, float* __restrict__ Cm,
                       float* __restrict__ E) {
    int row = blockIdx.x * 4 + (threadIdx.x >> 6);
    int lane = threadIdx.x & 63;
    const float* xr = x_act + (size_t)row * DI + lane * 8;
    float4 v0 = *(const float4*)xr;
    float4 v1 = *(const float4*)(xr + 4);
    float dtr = 0.0f;
    for (int j = 0; j < 2 * N + 1; ++j) {
        const float* wr = W_xp + (size_t)j * DI + lane * 8;
        float4 w0 = *(const float4*)wr;
        float4 w1 = *(const float4*)(wr + 4);
        float acc = v0.x * w0.x + v0.y * w0.y + v0.z * w0.z + v0.w * w0.w
                  + v1.x * w1.x + v1.y * w1.y + v1.z * w1.z + v1.w * w1.w;
        for (int m = 1; m < 64; m <<= 1) acc += __shfl_xor(acc, m);
        if (j == 0) dtr = acc;                 // all lanes hold full sum
        if (lane == 0) {
            if (j >= 1 && j < 1 + N) Bm[(size_t)row * N + (j - 1)] = acc;
            else if (j >= 1 + N)     Cm[(size_t)row * N + (j - 1 - N)] = acc;
        }
    }
    int d0 = lane * 8;
    float4 w0 = *(const float4*)(W_dt + d0);
    float4 w1 = *(const float4*)(W_dt + d0 + 4);
    float4 q0 = *(const float4*)(b_dt + d0);
    float4 q1 = *(const float4*)(b_dt + d0 + 4);
    float4 e0, e1;
    e0.x = 1.0f / (1.0f + __expf(dtr * w0.x + q0.x));
    e0.y = 1.0f / (1.0f + __expf(dtr * w0.y + q0.y));
    e0.z = 1.0f / (1.0f + __expf(dtr * w0.z + q0.z));
    e0.w = 1.0f / (1.0f + __expf(dtr * w0.w + q0.w));
    e1.x = 1.0f / (1.0f + __expf(dtr * w1.x + q1.x));
    e1.y = 1.0f / (1.0f + __expf(dtr * w1.y + q1.y));
    e1.z = 1.0f / (1.0f + __expf(dtr * w1.z + q1.z));
    e1.w = 1.0f / (1.0f + __expf(dtr * w1.w + q1.w));
    *(float4*)(E + (size_t)row * DI + d0) = e0;
    *(float4*)(E + (size_t)row * DI + d0 + 4) = e1;
}

// ---------------- rdeg = 1/max(sum_{s<t} adj,1); flag[t] ----------------
__global__ void deg_k(const float* __restrict__ adj, float* __restrict__ rdeg, int* __restrict__ flagI) {
    int t = blockIdx.x & (S - 1), b = blockIdx.x >> 9;
    int lane = threadIdx.x;
    const float* row = adj + ((size_t)(b * S + t)) * S;
    float s = 0.0f; bool anyp = false;
    for (int i = lane; i < t; i += 64) { float v = row[i]; s += v; anyp |= (v > 0.0f); }
    for (int m = 1; m < 64; m <<= 1) s += __shfl_xor(s, m);
    bool any = __any(anyp);
    if (lane == 0) {
        rdeg[b * S + t] = 1.0f / fmaxf(s, 1.0f);
        if (t > 0 && any) atomicOr(flagI + t, 1);
    }
}

// ================= dual-chunk fused kernel (256 threads, 384 blocks) =================
// Scan role uses 256 threads for staging, 128 for compute (waves 2-3 exit).
// Wr-mix done VALU-only via DPP row_ror (direction auto-probed).
// gpast role: barrier-free register-streaming MFMA.
#define SCAN32(RO, ADJT, GSUM)                                              \
    _Pragma("unroll")                                                       \
    for (int j = 0; j < CHUNK; ++j) {                                       \
        float e  = eL [((RO) + j) * 8 + grp];                               \
        float xa = xaL[((RO) + j) * 8 + grp];                               \
        float Bn = BnL[((RO) + j) * 16 + n];                                \
        h = h * e + xa * Bn;                                                \
        float g0 = GSUM[j], g1 = 0.f, g2 = 0.f, g3 = 0.f;                   \
        const float* ar = (ADJT) + j * 36;                                  \
        int sp = 0;                                                         \
        _Pragma("unroll")                                                   \
        for (; sp + 4 <= j; sp += 4) {                                      \
            float4 av = *(const float4*)(ar + sp);                          \
            g0 += av.x * hreg[sp];     g1 += av.y * hreg[sp + 1];           \
            g2 += av.z * hreg[sp + 2]; g3 += av.w * hreg[sp + 3];           \
        }                                                                   \
        _Pragma("unroll")                                                   \
        for (; sp < j; ++sp) g0 += ar[sp] * hreg[sp];                       \
        float gr = (g0 + g1) + (g2 + g3);                                   \
        float m0 = gr * wrr[0] + rork<4>(gr) * wrr[4]                       \
                 + rork<8>(gr) * wrr[8] + rork<12>(gr) * wrr[12];           \
        float m1 = rork<1>(gr) * wrr[1] + rork<5>(gr) * wrr[5]              \
                 + rork<9>(gr) * wrr[9] + rork<13>(gr) * wrr[13];           \
        float m2 = rork<2>(gr) * wrr[2] + rork<6>(gr) * wrr[6]              \
                 + rork<10>(gr) * wrr[10] + rork<14>(gr) * wrr[14];         \
        float m3 = rork<3>(gr) * wrr[3] + rork<7>(gr) * wrr[7]              \
                 + rork<11>(gr) * wrr[11] + rork<15>(gr) * wrr[15];         \
        float acc = fmaf(rdegL[(RO) + j], (m0 + m1) + (m2 + m3), brn);      \
        if (flL[(RO) + j]) h += 0.1f * acc / (1.0f + __expf(-acc));         \
        hreg[j] = h;                                                        \
    }

#define PRESUM(GSUM, PTR) {                                                 \
    const ushort16* _p = (PTR);                                             \
    _Pragma("unroll")                                                       \
    for (int qi = 0; qi < 4; ++qi) {                                        \
        uint4 q = *(const uint4*)(_p + qi * 8);                             \
        GSUM[qi*8+0] += bflo(q.x); GSUM[qi*8+1] += bfhi(q.x);               \
        GSUM[qi*8+2] += bflo(q.y); GSUM[qi*8+3] += bfhi(q.y);               \
        GSUM[qi*8+4] += bflo(q.z); GSUM[qi*8+5] += bfhi(q.z);               \
        GSUM[qi*8+6] += bflo(q.w); GSUM[qi*8+7] += bfhi(q.w);               \
    } }

__global__ __launch_bounds__(256) void chunk2_k(const float* __restrict__ adj,
                                                const float* __restrict__ x_act,
                                                const float* __restrict__ E,
                                                const float* __restrict__ Bm,
                                                const float* __restrict__ rdeg,
                                                const int* __restrict__ flagI,
                                                const float* __restrict__ Wr,
                                                const float* __restrict__ br,
                                                ushort16* __restrict__ Gall,
                                                ushort16* __restrict__ histT,
                                                float* __restrict__ hlast, int lc) {
    __shared__ __align__(16) char smem[56320];
    int tid = threadIdx.x;
    int cbA = 2 * lc * CHUNK;
    int cbB = cbA + CHUNK;
    const size_t SLOT = (size_t)B * DN * 32;
    int rp = lc & 1, wp = (lc + 1) & 1;

    if (blockIdx.x < 128) {
        // ---------------- scan role ----------------
        float* adjA  = (float*)smem;
        float* adjB  = (float*)(smem + 4608);
        short* AsM   = (short*)(smem + 9216);
        short* AsT   = (short*)(smem + 11776);
        float* eL    = (float*)(smem + 22016);
        float* xaL   = (float*)(smem + 24064);
        float* BnL   = (float*)(smem + 26112);
        float* rdegL = (float*)(smem + 30208);
        int*   flL   = (int*)  (smem + 30464);
        short* hTA   = (short*)(smem + 31232);
        float* Gmid  = (float*)(smem + 39424);
        short* hTB   = (short*)(smem + 39424);

        int b = blockIdx.x >> 6;
        int d0 = (blockIdx.x & 63) << 3;
        int n = tid & 15, grp = tid >> 4;     // for tid<128: grp 0..7
        int d = d0 + (grp & 7);
        int dn = d * N + n;
        int dnbase = (blockIdx.x & 63) << 7;

        // ---- stage (all 256 threads) ----
        {
            int j = tid >> 3, s4 = (tid & 7) * 4;
            {
                float4 a0 = *(const float4*)(adj + ((size_t)(b * S + cbA + j)) * S + cbA + s4);
                float* dp = adjA + j * 36 + s4;
                dp[0] = a0.x; dp[1] = a0.y; dp[2] = a0.z; dp[3] = a0.w;
            }
            {
                float4 a0 = *(const float4*)(adj + ((size_t)(b * S + cbB + j)) * S + cbB + s4);
                float* dp = adjB + j * 36 + s4;
                dp[0] = a0.x; dp[1] = a0.y; dp[2] = a0.z; dp[3] = a0.w;
            }
            {
                float4 a0 = *(const float4*)(adj + ((size_t)(b * S + cbB + j)) * S + cbA + s4);
                uint2 q; q.x = pk2(a0.x, a0.y); q.y = pk2(a0.z, a0.w);
                *(uint2*)&AsM[j * 40 + s4] = q;
            }
            if (lc < NL - 1) {
                #pragma unroll
                for (int st = 0; st < 4; ++st) {
                    int src = st >> 1, tgt = st & 1;
                    float4 a0 = *(const float4*)(adj + ((size_t)(b * S + cbA + 64 + 32 * tgt + j)) * S
                                                 + cbA + 32 * src + s4);
                    uint2 q; q.x = pk2(a0.x, a0.y); q.y = pk2(a0.z, a0.w);
                    *(uint2*)&AsT[(src * 2 + tgt) * 1280 + j * 40 + s4] = q;
                }
            }
            int jr = tid >> 2, dd = (tid & 3) * 2;
            float2 ev = *(const float2*)(E     + ((size_t)(b * S + cbA + jr)) * DI + d0 + dd);
            float2 xv = *(const float2*)(x_act + ((size_t)(b * S + cbA + jr)) * DI + d0 + dd);
            eL [jr * 8 + dd] = ev.x; eL [jr * 8 + dd + 1] = ev.y;
            xaL[jr * 8 + dd] = xv.x; xaL[jr * 8 + dd + 1] = xv.y;
            int nn = (tid & 3) * 4;
            float4 bv = *(const float4*)(Bm + ((size_t)(b * S + cbA + jr)) * N + nn);
            BnL[jr * 16 + nn] = bv.x; BnL[jr * 16 + nn + 1] = bv.y;
            BnL[jr * 16 + nn + 2] = bv.z; BnL[jr * 16 + nn + 3] = bv.w;
            if (tid < 64) {
                rdegL[tid] = rdeg[b * S + cbA + tid];
                flL[tid]   = flagI[cbA + tid];
            }
        }
        __syncthreads();
        if (tid >= 128) return;

        // ---- presum G (both chunks) ----
        float gsA[CHUNK], gsB[CHUNK];
        #pragma unroll
        for (int j = 0; j < CHUNK; ++j) { gsA[j] = 0.f; gsB[j] = 0.f; }
        {
            size_t tb = ((size_t)b * DN + dn) * 32;
            if (lc >= 2) {
                PRESUM(gsA, Gall + ((size_t)rp * 6 + 0) * SLOT + tb);
                PRESUM(gsB, Gall + ((size_t)rp * 6 + 1) * SLOT + tb);
            }
            if (lc >= 1) {
                PRESUM(gsA, Gall + ((size_t)rp * 6 + 2) * SLOT + tb);
                PRESUM(gsA, Gall + ((size_t)rp * 6 + 4) * SLOT + tb);
                PRESUM(gsB, Gall + ((size_t)rp * 6 + 3) * SLOT + tb);
                PRESUM(gsB, Gall + ((size_t)rp * 6 + 5) * SLOT + tb);
            }
        }

        // ---- Wr weights, DPP-direction-corrected ----
        int probe = __builtin_amdgcn_mov_dpp((int)n, 0x121, 0xf, 0xf, false);
        bool plusdir = (probe == ((n + 1) & 15));
        float wrr[16];
        #pragma unroll
        for (int k = 0; k < 16; ++k) {
            int ip = (n + k) & 15, im = (n - k + 16) & 15;
            wrr[k] = Wr[n * 16 + (plusdir ? ip : im)];
        }
        float brn = br[n];
        float h = (lc == 0) ? 0.0f : hlast[b * DN + dn];

        float hreg[CHUNK];
        // ======== scan chunk A ========
        SCAN32(0, adjA, gsA)

        {
            ushort16* ht = histT + ((size_t)b * DN + dn) * S + cbA;
            #pragma unroll
            for (int qi = 0; qi < 4; ++qi) {
                uint4 q;
                q.x = pk2(hreg[qi*8+0], hreg[qi*8+1]);
                q.y = pk2(hreg[qi*8+2], hreg[qi*8+3]);
                q.z = pk2(hreg[qi*8+4], hreg[qi*8+5]);
                q.w = pk2(hreg[qi*8+6], hreg[qi*8+7]);
                *(uint4*)(ht + qi * 8) = q;
                *(uint4*)&hTA[qi * 1024 + tid * 8] = q;
            }
        }
        __syncthreads();
        // ======== mid MFMA: adj(B rows, A cols) x histA -> Gmid (f32 LDS) ========
        {
            int w = tid >> 6, l = tid & 63;
            bf16x8 aF0 = *(const bf16x8*)&AsM[(l & 15) * 40 + (l >> 4) * 8];
            bf16x8 aF1 = *(const bf16x8*)&AsM[(16 + (l & 15)) * 40 + (l >> 4) * 8];
            #pragma unroll
            for (int dblk = 0; dblk < 4; ++dblk) {
                int col = w * 64 + dblk * 16 + (l & 15);
                bf16x8 bF = *(const bf16x8*)&hTA[(l >> 4) * 1024 + col * 8];
                f32x4 a0v = {0.f,0.f,0.f,0.f}, a1v = {0.f,0.f,0.f,0.f};
                a0v = __builtin_amdgcn_mfma_f32_16x16x32_bf16(aF0, bF, a0v, 0, 0, 0);
                a1v = __builtin_amdgcn_mfma_f32_16x16x32_bf16(aF1, bF, a1v, 0, 0, 0);
                int jb0 = (l >> 4) * 4;
                #pragma unroll
                for (int reg = 0; reg < 4; ++reg) {
                    Gmid[(jb0 + reg) * 129 + col]      = a0v[reg];
                    Gmid[(16 + jb0 + reg) * 129 + col] = a1v[reg];
                }
            }
        }
        __syncthreads();
        #pragma unroll
        for (int j = 0; j < CHUNK; ++j) gsB[j] += Gmid[j * 129 + tid];
        __syncthreads();

        // ======== scan chunk B ========
        SCAN32(32, adjB, gsB)
        hlast[b * DN + dn] = h;

        {
            ushort16* ht = histT + ((size_t)b * DN + dn) * S + cbB;
            #pragma unroll
            for (int qi = 0; qi < 4; ++qi) {
                uint4 q;
                q.x = pk2(hreg[qi*8+0], hreg[qi*8+1]);
                q.y = pk2(hreg[qi*8+2], hreg[qi*8+3]);
                q.z = pk2(hreg[qi*8+4], hreg[qi*8+5]);
                q.w = pk2(hreg[qi*8+6], hreg[qi*8+7]);
                *(uint4*)(ht + qi * 8) = q;
                *(uint4*)&hTB[qi * 1024 + tid * 8] = q;
            }
        }
        // ======== tails: {A,B} -> targets {2lc+2, 2lc+3} via MFMA ========
        if (lc < NL - 1) {
            __syncthreads();
            int w = tid >> 6, l = tid & 63;
            int jb0 = (l >> 4) * 4;
            #pragma unroll
            for (int src = 0; src < 2; ++src) {
                const short* hTs = src ? hTB : hTA;
                #pragma unroll
                for (int tgt = 0; tgt < 2; ++tgt) {
                    const short* At = AsT + (src * 2 + tgt) * 1280;
                    bf16x8 aF0 = *(const bf16x8*)&At[(l & 15) * 40 + (l >> 4) * 8];
                    bf16x8 aF1 = *(const bf16x8*)&At[(16 + (l & 15)) * 40 + (l >> 4) * 8];
                    ushort16* gw = Gall + ((size_t)wp * 6 + (2 + src * 2 + tgt)) * SLOT;
                    #pragma unroll
                    for (int dblk = 0; dblk < 4; ++dblk) {
                        int col = w * 64 + dblk * 16 + (l & 15);
                        bf16x8 bF = *(const bf16x8*)&hTs[(l >> 4) * 1024 + col * 8];
                        f32x4 a0v = {0.f,0.f,0.f,0.f}, a1v = {0.f,0.f,0.f,0.f};
                        a0v = __builtin_amdgcn_mfma_f32_16x16x32_bf16(aF0, bF, a0v, 0, 0, 0);
                        a1v = __builtin_amdgcn_mfma_f32_16x16x32_bf16(aF1, bF, a1v, 0, 0, 0);
                        int dng = dnbase + col;
                        uint2 o0, o1;
                        o0.x = pk2(a0v[0], a0v[1]); o0.y = pk2(a0v[2], a0v[3]);
                        o1.x = pk2(a1v[0], a1v[1]); o1.y = pk2(a1v[2], a1v[3]);
                        *(uint2*)(gw + ((size_t)b * DN + dng) * 32 + jb0) = o0;
                        *(uint2*)(gw + ((size_t)b * DN + dng) * 32 + 16 + jb0) = o1;
                    }
                }
            }
        }
    } else {
        // -------- gpast role: barrier-free register-streaming MFMA --------
        if (lc == 0 || lc >= NL - 1) return;
        int idx = blockIdx.x - 128;                // 0..255
        int tile = idx & 63;
        int b = (idx >> 6) & 1;
        int tgt = idx >> 7;
        int tc = 2 * lc + 2 + tgt;
        int dn0 = tile * 128;
        int w = tid >> 6, l = tid & 63;
        int jh = w & 1, dh = w >> 1;
        int kseg = (l >> 4) * 8;
        const float* abase = adj + ((size_t)(b * S + tc * CHUNK + jh * 16 + (l & 15))) * S + kseg;
        const ushort16* hbase = histT + ((size_t)b * DN + dn0 + dh * 64 + (l & 15)) * S + kseg;
        int K = 2 * lc;
        f32x4 acc[4] = {};
        #pragma unroll 2
        for (int ks = 0; ks < K; ++ks) {
            float4 af0 = *(const float4*)(abase + ks * 32);
            float4 af1 = *(const float4*)(abase + ks * 32 + 4);
            uint4 aP;
            aP.x = pk2(af0.x, af0.y); aP.y = pk2(af0.z, af0.w);
            aP.z = pk2(af1.x, af1.y); aP.w = pk2(af1.z, af1.w);
            bf16x8 aF;
            *(uint4*)&aF = aP;
            uint4 bP[4];
            #pragma unroll
            for (int dblk = 0; dblk < 4; ++dblk)
                bP[dblk] = *(const uint4*)(hbase + (size_t)(dblk * 16) * S + ks * 32);
            #pragma unroll
            for (int dblk = 0; dblk < 4; ++dblk) {
                bf16x8 bF;
                *(uint4*)&bF = bP[dblk];
                acc[dblk] = __builtin_amdgcn_mfma_f32_16x16x32_bf16(aF, bF, acc[dblk], 0, 0, 0);
            }
        }
        int jb = jh * 16 + (l >> 4) * 4;
        ushort16* gbase = Gall + ((size_t)wp * 6 + tgt) * SLOT;
        #pragma unroll
        for (int dblk = 0; dblk < 4; ++dblk) {
            int dnc = dn0 + dh * 64 + dblk * 16 + (l & 15);
            uint2 o;
            o.x = pk2(acc[dblk][0], acc[dblk][1]);
            o.y = pk2(acc[dblk][2], acc[dblk][3]);
            *(uint2*)(gbase + ((size_t)b * DN + dnc) * 32 + jb) = o;
        }
    }
}

// ---------------- y_k: y[b,t,d] = (sum_n histT[b][dn][t]*Cm[b,t,n]) * zs[b,t,d] -------
__global__ __launch_bounds__(256) void y_k(const ushort16* __restrict__ histT,
                                           const float* __restrict__ Cm,
                                           const float* __restrict__ zs,
                                           ushort16* __restrict__ yzb) {
    __shared__ float CmL[S * 17];
    int b = blockIdx.x >> 9;
    int d = blockIdx.x & (DI - 1);
    int tid = threadIdx.x;
    #pragma unroll
    for (int q = 0; q < 8; ++q) {
        int l0 = q * 1024 + tid * 4;
        int t = l0 >> 4, n0 = l0 & 15;
        float4 v = *(const float4*)(Cm + (size_t)b * S * N + l0);
        CmL[t * 17 + n0]     = v.x;
        CmL[t * 17 + n0 + 1] = v.y;
        CmL[t * 17 + n0 + 2] = v.z;
        CmL[t * 17 + n0 + 3] = v.w;
    }
    __syncthreads();
    const ushort16* hbase = histT + ((size_t)b * DN + d * N) * S;
    #pragma unroll
    for (int pass = 0; pass < 2; ++pass) {
        int t = pass * 256 + tid;
        float a0 = 0.f, a1 = 0.f, a2 = 0.f, a3 = 0.f;
        #pragma unroll
        for (int n = 0; n < 16; n += 4) {
            a0 += bf2f(hbase[(size_t)n * S + t])       * CmL[t * 17 + n];
            a1 += bf2f(hbase[(size_t)(n + 1) * S + t]) * CmL[t * 17 + n + 1];
            a2 += bf2f(hbase[(size_t)(n + 2) * S + t]) * CmL[t * 17 + n + 2];
            a3 += bf2f(hbase[(size_t)(n + 3) * S + t]) * CmL[t * 17 + n + 3];
        }
        float acc = (a0 + a1) + (a2 + a3);
        float zv = zs[((size_t)(b * S + t)) * DI + d];
        yzb[((size_t)(b * S + t)) * DI + d] = f2bf(acc * zv);
    }
}

// ---------------- launch ----------------
extern "C" void kernel_launch(void* const* d_in, const int* in_sizes, int n_in,
                              void* d_out, int out_size, void* d_ws, size_t ws_size,
                              hipStream_t stream) {
    const float* x      = (const float*)d_in[0];
    const float* adj    = (const float*)d_in[1];
    const float* ln_w   = (const float*)d_in[2];
    const float* ln_b   = (const float*)d_in[3];
    const float* W_in   = (const float*)d_in[4];
    const float* conv_w = (const float*)d_in[5];
    const float* conv_b = (const float*)d_in[6];
    const float* W_xp   = (const float*)d_in[7];
    const float* W_dt   = (const float*)d_in[8];
    const float* b_dt   = (const float*)d_in[9];
    const float* Wr     = (const float*)d_in[10];
    const float* br     = (const float*)d_in[11];
    const float* W_out  = (const float*)d_in[12];
    float* out = (float*)d_out;

    float* ws = (float*)d_ws;
    size_t off = 0;
    float* x_act  = ws + off; off += (size_t)B * S * DI;
    float* Bmb    = ws + off; off += (size_t)B * S * N;
    float* Cmb    = ws + off; off += (size_t)B * S * N;
    float* rdegp  = ws + off; off += (size_t)B * S;
    int*   flagI  = (int*)(ws + off); off += S;
    float* Ebuf   = ws + off; off += (size_t)B * S * DI;
    float* zsbuf  = ws + off; off += (size_t)B * S * DI;
    float* hlast  = ws + off; off += (size_t)B * DN;
    ushort16* xnb    = (ushort16*)(ws + off); off += (size_t)B * S * D / 2;
    ushort16* yzb    = (ushort16*)(ws + off); off += (size_t)B * S * DI / 2;
    ushort16* histT  = (ushort16*)(ws + off); off += (size_t)B * DN * S / 2;
    ushort16* Gall   = (ushort16*)(ws + off); off += (size_t)2 * 6 * B * DN * 32 / 2;
    ushort16* xpb    = (ushort16*)(ws + off); off += (size_t)B * (S + 3) * DI / 2;

    hipMemsetAsync(flagI, 0, S * sizeof(int), stream);
    hipMemsetAsync(xpb, 0, (size_t)B * (S + 3) * DI * 2, stream);

    ln_k<<<B * S, 64, 0, stream>>>(x, ln_w, ln_b, xnb);
    gemmb_k<1><<<dim3(2 * DI / 64, B * S / 64), 256, 0, stream>>>(
        xnb, W_in, nullptr, nullptr, xpb, zsbuf, B * S, 2 * DI, D);
    convm_k<<<dim3(DI / 32, B * S / 32), 256, 0, stream>>>(xpb, conv_w, conv_b, x_act);
    ssmE_k<<<B * S / 4, 256, 0, stream>>>(x_act, W_xp, W_dt, b_dt, Bmb, Cmb, Ebuf);
    deg_k<<<B * S, 64, 0, stream>>>(adj, rdegp, flagI);

    for (int lc = 0; lc < NL; ++lc)
        chunk2_k<<<384, 256, 0, stream>>>(adj, x_act, Ebuf, Bmb, rdegp, flagI,
                                          Wr, br, Gall, histT, hlast, lc);

    y_k<<<B * DI, 256, 0, stream>>>(histT, Cmb, zsbuf, yzb);

    gemmb_k<0><<<dim3(D / 64, B * S / 64), 256, 0, stream>>>(
        yzb, W_out, x, out, nullptr, nullptr, B * S, D, DI);
}

// Round 13
// 265.468 us; speedup vs baseline: 4.3914x; 1.0466x over previous
//
#include <hip/hip_runtime.h>
#include <math.h>

// Problem constants
static constexpr int B  = 2;
static constexpr int S  = 512;
static constexpr int D  = 256;
static constexpr int N  = 16;
static constexpr int DI = 512;
static constexpr int CHUNK = 32;
static constexpr int NCHUNK = S / CHUNK;   // 16
static constexpr int NL = NCHUNK / 2;      // 8 launches, 2 chunks each
static constexpr int DN = DI * N;          // 8192
static constexpr int NSLOT = 8;            // 4 gold (tgt*2+kh) + 4 tails (4+src*2+tgt)

typedef unsigned int uint32;
typedef unsigned short ushort16;
using bf16x8 = __attribute__((ext_vector_type(8))) short;
using f32x4  = __attribute__((ext_vector_type(4))) float;

__device__ __forceinline__ ushort16 f2bf(float f) {
    uint32 u = __float_as_uint(f);
    u = (u + 0x7fffu + ((u >> 16) & 1u)) >> 16;   // RNE
    return (ushort16)u;
}
__device__ __forceinline__ float bflo(uint32 u) { return __uint_as_float(u << 16); }
__device__ __forceinline__ float bfhi(uint32 u) { return __uint_as_float(u & 0xffff0000u); }
__device__ __forceinline__ float bf2f(ushort16 u) { return __uint_as_float(((uint32)u) << 16); }
__device__ __forceinline__ uint32 pk2(float a, float b) {
    return (uint32)(ushort16)f2bf(a) | ((uint32)(ushort16)f2bf(b) << 16);
}
// DPP row-rotate within 16-lane rows (VALU pipe, no LDS)
template<int K>
__device__ __forceinline__ float rork(float x) {
    return __uint_as_float((uint32)__builtin_amdgcn_mov_dpp(
        (int)__float_as_uint(x), 0x120 + K, 0xf, 0xf, false));
}
// histT tiled layout: elem (b, dn, s) -> ((b*(S/32) + s/32)*DN + dn)*32 + s%32
__device__ __forceinline__ size_t htIdx(int b, int dn, int sb) {
    return ((size_t)(b * (S / 32) + sb) * DN + dn) * 32;
}

// ---------------- LayerNorm: one wave per row, bf16 output ----------------
__global__ void ln_k(const float* __restrict__ x, const float* __restrict__ w,
                     const float* __restrict__ bias, ushort16* __restrict__ xnb) {
    int row = blockIdx.x;
    int lane = threadIdx.x;
    float4 v = *(const float4*)(x + row * D + lane * 4);
    float s = v.x + v.y + v.z + v.w;
    float q = v.x * v.x + v.y * v.y + v.z * v.z + v.w * v.w;
    for (int m = 1; m < 64; m <<= 1) { s += __shfl_xor(s, m); q += __shfl_xor(q, m); }
    float mu  = s * (1.0f / D);
    float var = q * (1.0f / D) - mu * mu;
    float rs  = rsqrtf(var + 1e-5f);
    float4 wv = *(const float4*)(w + lane * 4);
    float4 bv = *(const float4*)(bias + lane * 4);
    float4 o;
    o.x = (v.x - mu) * rs * wv.x + bv.x;
    o.y = (v.y - mu) * rs * wv.y + bv.y;
    o.z = (v.z - mu) * rs * wv.z + bv.z;
    o.w = (v.w - mu) * rs * wv.w + bv.w;
    uint2 pk;
    pk.x = pk2(o.x, o.y);
    pk.y = pk2(o.z, o.w);
    *(uint2*)(xnb + row * D + lane * 4) = pk;
}

// ------- bf16 MFMA GEMM, W in f32 (converted during staging) -------
template<int MODE>
__global__ __launch_bounds__(256) void gemmb_k(const ushort16* __restrict__ A,
                                               const float* __restrict__ W,
                                               const float* __restrict__ res,
                                               float* __restrict__ C,
                                               ushort16* __restrict__ xpb,
                                               float* __restrict__ zs,
                                               int M, int Nc, int K) {
    __shared__ __align__(16) short As[64 * 40];
    __shared__ __align__(16) short Ws[64 * 40];
    int tid = threadIdx.x;
    int l = tid & 63, wid = tid >> 6;
    int wm = wid & 1, wn = wid >> 1;
    int row0 = blockIdx.y * 64, col0 = blockIdx.x * 64;
    int r = tid >> 2, kseg = (tid & 3) * 8;
    f32x4 acc[2][2] = {};
    for (int k0 = 0; k0 < K; k0 += 32) {
        *(uint4*)&As[r * 40 + kseg] = *(const uint4*)(A + (size_t)(row0 + r) * K + k0 + kseg);
        {
            const float* wrow = W + (size_t)(col0 + r) * K + k0 + kseg;
            float4 w0 = *(const float4*)wrow;
            float4 w1 = *(const float4*)(wrow + 4);
            uint4 q;
            q.x = pk2(w0.x, w0.y); q.y = pk2(w0.z, w0.w);
            q.z = pk2(w1.x, w1.y); q.w = pk2(w1.z, w1.w);
            *(uint4*)&Ws[r * 40 + kseg] = q;
        }
        __syncthreads();
        bf16x8 aF[2], bF[2];
        #pragma unroll
        for (int am = 0; am < 2; ++am)
            aF[am] = *(const bf16x8*)&As[(wm * 32 + am * 16 + (l & 15)) * 40 + (l >> 4) * 8];
        #pragma unroll
        for (int bn = 0; bn < 2; ++bn)
            bF[bn] = *(const bf16x8*)&Ws[(wn * 32 + bn * 16 + (l & 15)) * 40 + (l >> 4) * 8];
        #pragma unroll
        for (int am = 0; am < 2; ++am)
            #pragma unroll
            for (int bn = 0; bn < 2; ++bn)
                acc[am][bn] = __builtin_amdgcn_mfma_f32_16x16x32_bf16(aF[am], bF[bn], acc[am][bn], 0, 0, 0);
        __syncthreads();
    }
    #pragma unroll
    for (int am = 0; am < 2; ++am)
        #pragma unroll
        for (int bn = 0; bn < 2; ++bn) {
            int cc = col0 + wn * 32 + bn * 16 + (l & 15);
            #pragma unroll
            for (int reg = 0; reg < 4; ++reg) {
                int rr = row0 + wm * 32 + am * 16 + (l >> 4) * 4 + reg;
                float v = acc[am][bn][reg];
                if (MODE == 0) {
                    if (res) v += res[(size_t)rr * Nc + cc];
                    C[(size_t)rr * Nc + cc] = v;
                } else {
                    int b = rr >> 9, t = rr & (S - 1);
                    if (cc < DI)
                        xpb[((size_t)(b * (S + 3) + 3 + t)) * DI + cc] = f2bf(v);
                    else
                        zs[((size_t)(b * S + t)) * DI + (cc - DI)] = v / (1.0f + __expf(-v));
                }
            }
        }
}

// ---------------- Causal conv via bf16 MFMA + bias + silu ----------------
__global__ __launch_bounds__(256) void convm_k(const ushort16* __restrict__ xpb,
                                               const float* __restrict__ conv_w,
                                               const float* __restrict__ conv_b,
                                               float* __restrict__ x_act) {
    __shared__ __align__(16) short AxS[35 * 40];
    __shared__ __align__(16) short WbS[4 * 32 * 40];
    int tid = threadIdx.x;
    int l = tid & 63, wid = tid >> 6;
    int wm = wid & 1, wn = wid >> 1;
    int o0 = blockIdx.x * 32;
    int mt = blockIdx.y;
    int b = mt >> 4, tl0 = (mt & 15) * 32;
    f32x4 acc = {0.f, 0.f, 0.f, 0.f};

    for (int k0 = 0; k0 < DI; k0 += 32) {
        if (tid < 140) {
            int rr = tid >> 2, seg = tid & 3;
            uint4 v = *(const uint4*)(xpb + ((size_t)(b * (S + 3) + tl0 + rr)) * DI + k0 + seg * 8);
            *(uint4*)&AxS[rr * 40 + seg * 8] = v;
        }
        #pragma unroll
        for (int it = 0; it < 4; ++it) {
            int p = it * 256 + tid;
            int o = p >> 5, i = p & 31;
            float4 w4 = *(const float4*)(conv_w + ((size_t)(o0 + o) * DI + (k0 + i)) * 4);
            WbS[(0 * 32 + o) * 40 + i] = (short)f2bf(w4.x);
            WbS[(1 * 32 + o) * 40 + i] = (short)f2bf(w4.y);
            WbS[(2 * 32 + o) * 40 + i] = (short)f2bf(w4.z);
            WbS[(3 * 32 + o) * 40 + i] = (short)f2bf(w4.w);
        }
        __syncthreads();
        #pragma unroll
        for (int k = 0; k < 4; ++k) {
            bf16x8 aF = *(const bf16x8*)&AxS[(wm * 16 + (l & 15) + k) * 40 + (l >> 4) * 8];
            bf16x8 bF = *(const bf16x8*)&WbS[(k * 32 + wn * 16 + (l & 15)) * 40 + (l >> 4) * 8];
            acc = __builtin_amdgcn_mfma_f32_16x16x32_bf16(aF, bF, acc, 0, 0, 0);
        }
        __syncthreads();
    }
    int oc = o0 + wn * 16 + (l & 15);
    float bia = conv_b[oc];
    #pragma unroll
    for (int reg = 0; reg < 4; ++reg) {
        int m = wm * 16 + (l >> 4) * 4 + reg;
        float v = acc[reg] + bia;
        x_act[((size_t)(b * S + tl0 + m)) * DI + oc] = v / (1.0f + __expf(-v));
    }
}

// ------- ssm (33 outputs) + E epilogue -------
__global__ void ssmE_k(const float* __restrict__ x_act, const float* __restrict__ W_xp,
                       const float* __restrict__ W_dt, const float* __restrict__ b_dt,
                       float* __restrict__ Bm, float* __restrict__ Cm,
                       float* __restrict__ E) {
    int row = blockIdx.x * 4 + (threadIdx.x >> 6);
    int lane = threadIdx.x & 63;
    const float* xr = x_act + (size_t)row * DI + lane * 8;
    float4 v0 = *(const float4*)xr;
    float4 v1 = *(const float4*)(xr + 4);
    float dtr = 0.0f;
    for (int j = 0; j < 2 * N + 1; ++j) {
        const float* wr = W_xp + (size_t)j * DI + lane * 8;
        float4 w0 = *(const float4*)wr;
        float4 w1 = *(const float4*)(wr + 4);
        float acc = v0.x * w0.x + v0.y * w0.y + v0.z * w0.z + v0.w * w0.w
                  + v1.x * w1.x + v1.y * w1.y + v1.z * w1.z + v1.w * w1.w;
        for (int m = 1; m < 64; m <<= 1) acc += __shfl_xor(acc, m);
        if (j == 0) dtr = acc;
        if (lane == 0) {
            if (j >= 1 && j < 1 + N) Bm[(size_t)row * N + (j - 1)] = acc;
            else if (j >= 1 + N)     Cm[(size_t)row * N + (j - 1 - N)] = acc;
        }
    }
    int d0 = lane * 8;
    float4 w0 = *(const float4*)(W_dt + d0);
    float4 w1 = *(const float4*)(W_dt + d0 + 4);
    float4 q0 = *(const float4*)(b_dt + d0);
    float4 q1 = *(const float4*)(b_dt + d0 + 4);
    float4 e0, e1;
    e0.x = 1.0f / (1.0f + __expf(dtr * w0.x + q0.x));
    e0.y = 1.0f / (1.0f + __expf(dtr * w0.y + q0.y));
    e0.z = 1.0f / (1.0f + __expf(dtr * w0.z + q0.z));
    e0.w = 1.0f / (1.0f + __expf(dtr * w0.w + q0.w));
    e1.x = 1.0f / (1.0f + __expf(dtr * w1.x + q1.x));
    e1.y = 1.0f / (1.0f + __expf(dtr * w1.y + q1.y));
    e1.z = 1.0f / (1.0f + __expf(dtr * w1.z + q1.z));
    e1.w = 1.0f / (1.0f + __expf(dtr * w1.w + q1.w));
    *(float4*)(E + (size_t)row * DI + d0) = e0;
    *(float4*)(E + (size_t)row * DI + d0 + 4) = e1;
}

// ---------------- rdeg = 1/max(sum_{s<t} adj,1); flag[t] ----------------
__global__ void deg_k(const float* __restrict__ adj, float* __restrict__ rdeg, int* __restrict__ flagI) {
    int t = blockIdx.x & (S - 1), b = blockIdx.x >> 9;
    int lane = threadIdx.x;
    const float* row = adj + ((size_t)(b * S + t)) * S;
    float s = 0.0f; bool anyp = false;
    for (int i = lane; i < t; i += 64) { float v = row[i]; s += v; anyp |= (v > 0.0f); }
    for (int m = 1; m < 64; m <<= 1) s += __shfl_xor(s, m);
    bool any = __any(anyp);
    if (lane == 0) {
        rdeg[b * S + t] = 1.0f / fmaxf(s, 1.0f);
        if (t > 0 && any) atomicOr(flagI + t, 1);
    }
}

// ================= dual-chunk fused kernel (256 threads, 640 blocks) =================
#define SCAN32(RO, ADJT, GSUM)                                              \
    _Pragma("unroll")                                                       \
    for (int j = 0; j < CHUNK; ++j) {                                       \
        float e  = eL [((RO) + j) * 8 + grp];                               \
        float xa = xaL[((RO) + j) * 8 + grp];                               \
        float Bn = BnL[((RO) + j) * 16 + n];                                \
        h = h * e + xa * Bn;                                                \
        float g0 = GSUM[j], g1 = 0.f, g2 = 0.f, g3 = 0.f;                   \
        const float* ar = (ADJT) + j * 36;                                  \
        int sp = 0;                                                         \
        _Pragma("unroll")                                                   \
        for (; sp + 4 <= j; sp += 4) {                                      \
            float4 av = *(const float4*)(ar + sp);                          \
            g0 += av.x * hreg[sp];     g1 += av.y * hreg[sp + 1];           \
            g2 += av.z * hreg[sp + 2]; g3 += av.w * hreg[sp + 3];           \
        }                                                                   \
        _Pragma("unroll")                                                   \
        for (; sp < j; ++sp) g0 += ar[sp] * hreg[sp];                       \
        float gr = (g0 + g1) + (g2 + g3);                                   \
        float m0 = gr * wrr[0] + rork<4>(gr) * wrr[4]                       \
                 + rork<8>(gr) * wrr[8] + rork<12>(gr) * wrr[12];           \
        float m1 = rork<1>(gr) * wrr[1] + rork<5>(gr) * wrr[5]              \
                 + rork<9>(gr) * wrr[9] + rork<13>(gr) * wrr[13];           \
        float m2 = rork<2>(gr) * wrr[2] + rork<6>(gr) * wrr[6]              \
                 + rork<10>(gr) * wrr[10] + rork<14>(gr) * wrr[14];         \
        float m3 = rork<3>(gr) * wrr[3] + rork<7>(gr) * wrr[7]              \
                 + rork<11>(gr) * wrr[11] + rork<15>(gr) * wrr[15];         \
        float acc = fmaf(rdegL[(RO) + j], (m0 + m1) + (m2 + m3), brn);      \
        if (flL[(RO) + j])                                                  \
            h = fmaf(0.1f * acc,                                            \
                     __builtin_amdgcn_rcpf(1.0f + __expf(-acc)), h);        \
        hreg[j] = h;                                                        \
    }

#define PRESUM(GSUM, PTR) {                                                 \
    const ushort16* _p = (PTR);                                             \
    _Pragma("unroll")                                                       \
    for (int qi = 0; qi < 4; ++qi) {                                        \
        uint4 q = *(const uint4*)(_p + qi * 8);                             \
        GSUM[qi*8+0] += bflo(q.x); GSUM[qi*8+1] += bfhi(q.x);               \
        GSUM[qi*8+2] += bflo(q.y); GSUM[qi*8+3] += bfhi(q.y);               \
        GSUM[qi*8+4] += bflo(q.z); GSUM[qi*8+5] += bfhi(q.z);               \
        GSUM[qi*8+6] += bflo(q.w); GSUM[qi*8+7] += bfhi(q.w);               \
    } }

__global__ __launch_bounds__(256) void chunk2_k(const float* __restrict__ adj,
                                                const float* __restrict__ x_act,
                                                const float* __restrict__ E,
                                                const float* __restrict__ Bm,
                                                const float* __restrict__ rdeg,
                                                const int* __restrict__ flagI,
                                                const float* __restrict__ Wr,
                                                const float* __restrict__ br,
                                                ushort16* __restrict__ Gall,
                                                ushort16* __restrict__ histT,
                                                float* __restrict__ hlast, int lc) {
    __shared__ __align__(16) char smem[56320];
    int tid = threadIdx.x;
    int cbA = 2 * lc * CHUNK;
    int cbB = cbA + CHUNK;
    const size_t SLOT = (size_t)B * DN * 32;
    int rp = lc & 1, wp = (lc + 1) & 1;

    if (blockIdx.x < 128) {
        // ---------------- scan role ----------------
        float* adjA  = (float*)smem;
        float* adjB  = (float*)(smem + 4608);
        short* AsM   = (short*)(smem + 9216);
        short* AsT   = (short*)(smem + 11776);
        float* eL    = (float*)(smem + 22016);
        float* xaL   = (float*)(smem + 24064);
        float* BnL   = (float*)(smem + 26112);
        float* rdegL = (float*)(smem + 30208);
        int*   flL   = (int*)  (smem + 30464);
        short* hTA   = (short*)(smem + 31232);
        float* Gmid  = (float*)(smem + 39424);
        short* hTB   = (short*)(smem + 39424);

        int b = blockIdx.x >> 6;
        int d0 = (blockIdx.x & 63) << 3;
        int n = tid & 15, grp = tid >> 4;     // for tid<128: grp 0..7
        int d = d0 + (grp & 7);
        int dn = d * N + n;
        int dnbase = (blockIdx.x & 63) << 7;

        // ---- stage (all 256 threads) ----
        {
            int j = tid >> 3, s4 = (tid & 7) * 4;
            {
                float4 a0 = *(const float4*)(adj + ((size_t)(b * S + cbA + j)) * S + cbA + s4);
                float* dp = adjA + j * 36 + s4;
                dp[0] = a0.x; dp[1] = a0.y; dp[2] = a0.z; dp[3] = a0.w;
            }
            {
                float4 a0 = *(const float4*)(adj + ((size_t)(b * S + cbB + j)) * S + cbB + s4);
                float* dp = adjB + j * 36 + s4;
                dp[0] = a0.x; dp[1] = a0.y; dp[2] = a0.z; dp[3] = a0.w;
            }
            {
                float4 a0 = *(const float4*)(adj + ((size_t)(b * S + cbB + j)) * S + cbA + s4);
                uint2 q; q.x = pk2(a0.x, a0.y); q.y = pk2(a0.z, a0.w);
                *(uint2*)&AsM[j * 40 + s4] = q;
            }
            if (lc < NL - 1) {
                #pragma unroll
                for (int st = 0; st < 4; ++st) {
                    int src = st >> 1, tgt = st & 1;
                    float4 a0 = *(const float4*)(adj + ((size_t)(b * S + cbA + 64 + 32 * tgt + j)) * S
                                                 + cbA + 32 * src + s4);
                    uint2 q; q.x = pk2(a0.x, a0.y); q.y = pk2(a0.z, a0.w);
                    *(uint2*)&AsT[(src * 2 + tgt) * 1280 + j * 40 + s4] = q;
                }
            }
            int jr = tid >> 2, dd = (tid & 3) * 2;
            float2 ev = *(const float2*)(E     + ((size_t)(b * S + cbA + jr)) * DI + d0 + dd);
            float2 xv = *(const float2*)(x_act + ((size_t)(b * S + cbA + jr)) * DI + d0 + dd);
            eL [jr * 8 + dd] = ev.x; eL [jr * 8 + dd + 1] = ev.y;
            xaL[jr * 8 + dd] = xv.x; xaL[jr * 8 + dd + 1] = xv.y;
            int nn = (tid & 3) * 4;
            float4 bv = *(const float4*)(Bm + ((size_t)(b * S + cbA + jr)) * N + nn);
            BnL[jr * 16 + nn] = bv.x; BnL[jr * 16 + nn + 1] = bv.y;
            BnL[jr * 16 + nn + 2] = bv.z; BnL[jr * 16 + nn + 3] = bv.w;
            if (tid < 64) {
                rdegL[tid] = rdeg[b * S + cbA + tid];
                flL[tid]   = flagI[cbA + tid];
            }
        }
        __syncthreads();
        if (tid >= 128) return;

        // ---- presum G (both chunks) ----
        float gsA[CHUNK], gsB[CHUNK];
        #pragma unroll
        for (int j = 0; j < CHUNK; ++j) { gsA[j] = 0.f; gsB[j] = 0.f; }
        {
            size_t tb = ((size_t)b * DN + dn) * 32;
            if (lc >= 2) {
                PRESUM(gsA, Gall + ((size_t)rp * NSLOT + 0) * SLOT + tb);   // gold t0 kh0
                PRESUM(gsA, Gall + ((size_t)rp * NSLOT + 1) * SLOT + tb);   // gold t0 kh1
                PRESUM(gsB, Gall + ((size_t)rp * NSLOT + 2) * SLOT + tb);   // gold t1 kh0
                PRESUM(gsB, Gall + ((size_t)rp * NSLOT + 3) * SLOT + tb);   // gold t1 kh1
            }
            if (lc >= 1) {
                PRESUM(gsA, Gall + ((size_t)rp * NSLOT + 4) * SLOT + tb);   // src0->t0
                PRESUM(gsA, Gall + ((size_t)rp * NSLOT + 6) * SLOT + tb);   // src1->t0
                PRESUM(gsB, Gall + ((size_t)rp * NSLOT + 5) * SLOT + tb);   // src0->t1
                PRESUM(gsB, Gall + ((size_t)rp * NSLOT + 7) * SLOT + tb);   // src1->t1
            }
        }

        // ---- Wr weights, DPP-direction-corrected ----
        int probe = __builtin_amdgcn_mov_dpp((int)n, 0x121, 0xf, 0xf, false);
        bool plusdir = (probe == ((n + 1) & 15));
        float wrr[16];
        #pragma unroll
        for (int k = 0; k < 16; ++k) {
            int ip = (n + k) & 15, im = (n - k + 16) & 15;
            wrr[k] = Wr[n * 16 + (plusdir ? ip : im)];
        }
        float brn = br[n];
        float h = (lc == 0) ? 0.0f : hlast[b * DN + dn];

        float hreg[CHUNK];
        // ======== scan chunk A ========
        SCAN32(0, adjA, gsA)

        {
            ushort16* ht = histT + htIdx(b, dn, 2 * lc);
            #pragma unroll
            for (int qi = 0; qi < 4; ++qi) {
                uint4 q;
                q.x = pk2(hreg[qi*8+0], hreg[qi*8+1]);
                q.y = pk2(hreg[qi*8+2], hreg[qi*8+3]);
                q.z = pk2(hreg[qi*8+4], hreg[qi*8+5]);
                q.w = pk2(hreg[qi*8+6], hreg[qi*8+7]);
                *(uint4*)(ht + qi * 8) = q;
                *(uint4*)&hTA[qi * 1024 + tid * 8] = q;
            }
        }
        __syncthreads();
        // ======== mid MFMA: adj(B rows, A cols) x histA -> Gmid (f32 LDS) ========
        {
            int w = tid >> 6, l = tid & 63;
            bf16x8 aF0 = *(const bf16x8*)&AsM[(l & 15) * 40 + (l >> 4) * 8];
            bf16x8 aF1 = *(const bf16x8*)&AsM[(16 + (l & 15)) * 40 + (l >> 4) * 8];
            #pragma unroll
            for (int dblk = 0; dblk < 4; ++dblk) {
                int col = w * 64 + dblk * 16 + (l & 15);
                bf16x8 bF = *(const bf16x8*)&hTA[(l >> 4) * 1024 + col * 8];
                f32x4 a0v = {0.f,0.f,0.f,0.f}, a1v = {0.f,0.f,0.f,0.f};
                a0v = __builtin_amdgcn_mfma_f32_16x16x32_bf16(aF0, bF, a0v, 0, 0, 0);
                a1v = __builtin_amdgcn_mfma_f32_16x16x32_bf16(aF1, bF, a1v, 0, 0, 0);
                int jb0 = (l >> 4) * 4;
                #pragma unroll
                for (int reg = 0; reg < 4; ++reg) {
                    Gmid[(jb0 + reg) * 129 + col]      = a0v[reg];
                    Gmid[(16 + jb0 + reg) * 129 + col] = a1v[reg];
                }
            }
        }
        __syncthreads();
        #pragma unroll
        for (int j = 0; j < CHUNK; ++j) gsB[j] += Gmid[j * 129 + tid];
        __syncthreads();

        // ======== scan chunk B ========
        SCAN32(32, adjB, gsB)
        hlast[b * DN + dn] = h;

        {
            ushort16* ht = histT + htIdx(b, dn, 2 * lc + 1);
            #pragma unroll
            for (int qi = 0; qi < 4; ++qi) {
                uint4 q;
                q.x = pk2(hreg[qi*8+0], hreg[qi*8+1]);
                q.y = pk2(hreg[qi*8+2], hreg[qi*8+3]);
                q.z = pk2(hreg[qi*8+4], hreg[qi*8+5]);
                q.w = pk2(hreg[qi*8+6], hreg[qi*8+7]);
                *(uint4*)(ht + qi * 8) = q;
                *(uint4*)&hTB[qi * 1024 + tid * 8] = q;
            }
        }
        // ======== tails: {A,B} -> targets {2lc+2, 2lc+3} via MFMA ========
        if (lc < NL - 1) {
            __syncthreads();
            int w = tid >> 6, l = tid & 63;
            int jb0 = (l >> 4) * 4;
            #pragma unroll
            for (int src = 0; src < 2; ++src) {
                const short* hTs = src ? hTB : hTA;
                #pragma unroll
                for (int tgt = 0; tgt < 2; ++tgt) {
                    const short* At = AsT + (src * 2 + tgt) * 1280;
                    bf16x8 aF0 = *(const bf16x8*)&At[(l & 15) * 40 + (l >> 4) * 8];
                    bf16x8 aF1 = *(const bf16x8*)&At[(16 + (l & 15)) * 40 + (l >> 4) * 8];
                    ushort16* gw = Gall + ((size_t)wp * NSLOT + (4 + src * 2 + tgt)) * SLOT;
                    #pragma unroll
                    for (int dblk = 0; dblk < 4; ++dblk) {
                        int col = w * 64 + dblk * 16 + (l & 15);
                        bf16x8 bF = *(const bf16x8*)&hTs[(l >> 4) * 1024 + col * 8];
                        f32x4 a0v = {0.f,0.f,0.f,0.f}, a1v = {0.f,0.f,0.f,0.f};
                        a0v = __builtin_amdgcn_mfma_f32_16x16x32_bf16(aF0, bF, a0v, 0, 0, 0);
                        a1v = __builtin_amdgcn_mfma_f32_16x16x32_bf16(aF1, bF, a1v, 0, 0, 0);
                        int dng = dnbase + col;
                        uint2 o0, o1;
                        o0.x = pk2(a0v[0], a0v[1]); o0.y = pk2(a0v[2], a0v[3]);
                        o1.x = pk2(a1v[0], a1v[1]); o1.y = pk2(a1v[2], a1v[3]);
                        *(uint2*)(gw + ((size_t)b * DN + dng) * 32 + jb0) = o0;
                        *(uint2*)(gw + ((size_t)b * DN + dng) * 32 + 16 + jb0) = o1;
                    }
                }
            }
        }
    } else {
        // -------- gpast role: barrier-free register-streaming MFMA, k-split x2 --------
        if (lc == 0 || lc >= NL - 1) return;
        int idx = blockIdx.x - 128;                // 0..511
        int tile = idx & 63;
        int b = (idx >> 6) & 1;
        int tgt = (idx >> 7) & 1;
        int kh = idx >> 8;
        int tc = 2 * lc + 2 + tgt;
        int ks0 = kh ? lc : 0;
        int ks1 = kh ? 2 * lc : lc;
        int dn0 = tile * 128;
        int w = tid >> 6, l = tid & 63;
        int jh = w & 1, dh = w >> 1;
        int kseg = (l >> 4) * 8;
        const float* abase = adj + ((size_t)(b * S + tc * CHUNK + jh * 16 + (l & 15))) * S + kseg;
        int dnrow = dn0 + dh * 64 + (l & 15);
        f32x4 acc[4] = {};
        #pragma unroll 2
        for (int ks = ks0; ks < ks1; ++ks) {
            float4 af0 = *(const float4*)(abase + ks * 32);
            float4 af1 = *(const float4*)(abase + ks * 32 + 4);
            uint4 aP;
            aP.x = pk2(af0.x, af0.y); aP.y = pk2(af0.z, af0.w);
            aP.z = pk2(af1.x, af1.y); aP.w = pk2(af1.z, af1.w);
            bf16x8 aF;
            *(uint4*)&aF = aP;
            uint4 bP[4];
            #pragma unroll
            for (int dblk = 0; dblk < 4; ++dblk)
                bP[dblk] = *(const uint4*)(histT + htIdx(b, dnrow + dblk * 16, ks) + kseg);
            #pragma unroll
            for (int dblk = 0; dblk < 4; ++dblk) {
                bf16x8 bF;
                *(uint4*)&bF = bP[dblk];
                acc[dblk] = __builtin_amdgcn_mfma_f32_16x16x32_bf16(aF, bF, acc[dblk], 0, 0, 0);
            }
        }
        int jb = jh * 16 + (l >> 4) * 4;
        ushort16* gbase = Gall + ((size_t)wp * NSLOT + (tgt * 2 + kh)) * SLOT;
        #pragma unroll
        for (int dblk = 0; dblk < 4; ++dblk) {
            int dnc = dn0 + dh * 64 + dblk * 16 + (l & 15);
            uint2 o;
            o.x = pk2(acc[dblk][0], acc[dblk][1]);
            o.y = pk2(acc[dblk][2], acc[dblk][3]);
            *(uint2*)(gbase + ((size_t)b * DN + dnc) * 32 + jb) = o;
        }
    }
}

// ---------------- y_k: y[b,t,d] = (sum_n histT[b][dn][t]*Cm[b,t,n]) * zs[b,t,d] -------
__global__ __launch_bounds__(256) void y_k(const ushort16* __restrict__ histT,
                                           const float* __restrict__ Cm,
                                           const float* __restrict__ zs,
                                           ushort16* __restrict__ yzb) {
    __shared__ float CmL[S * 17];
    int b = blockIdx.x >> 9;
    int d = blockIdx.x & (DI - 1);
    int tid = threadIdx.x;
    #pragma unroll
    for (int q = 0; q < 8; ++q) {
        int l0 = q * 1024 + tid * 4;
        int t = l0 >> 4, n0 = l0 & 15;
        float4 v = *(const float4*)(Cm + (size_t)b * S * N + l0);
        CmL[t * 17 + n0]     = v.x;
        CmL[t * 17 + n0 + 1] = v.y;
        CmL[t * 17 + n0 + 2] = v.z;
        CmL[t * 17 + n0 + 3] = v.w;
    }
    __syncthreads();
    #pragma unroll
    for (int pass = 0; pass < 2; ++pass) {
        int t = pass * 256 + tid;
        int sb = t >> 5, si = t & 31;
        const ushort16* hb = histT + htIdx(b, d * N, sb) + si;
        float a0 = 0.f, a1 = 0.f, a2 = 0.f, a3 = 0.f;
        #pragma unroll
        for (int n = 0; n < 16; n += 4) {
            a0 += bf2f(hb[(size_t)n * 32])       * CmL[t * 17 + n];
            a1 += bf2f(hb[(size_t)(n + 1) * 32]) * CmL[t * 17 + n + 1];
            a2 += bf2f(hb[(size_t)(n + 2) * 32]) * CmL[t * 17 + n + 2];
            a3 += bf2f(hb[(size_t)(n + 3) * 32]) * CmL[t * 17 + n + 3];
        }
        float acc = (a0 + a1) + (a2 + a3);
        float zv = zs[((size_t)(b * S + t)) * DI + d];
        yzb[((size_t)(b * S + t)) * DI + d] = f2bf(acc * zv);
    }
}

// ---------------- launch ----------------
extern "C" void kernel_launch(void* const* d_in, const int* in_sizes, int n_in,
                              void* d_out, int out_size, void* d_ws, size_t ws_size,
                              hipStream_t stream) {
    const float* x      = (const float*)d_in[0];
    const float* adj    = (const float*)d_in[1];
    const float* ln_w   = (const float*)d_in[2];
    const float* ln_b   = (const float*)d_in[3];
    const float* W_in   = (const float*)d_in[4];
    const float* conv_w = (const float*)d_in[5];
    const float* conv_b = (const float*)d_in[6];
    const float* W_xp   = (const float*)d_in[7];
    const float* W_dt   = (const float*)d_in[8];
    const float* b_dt   = (const float*)d_in[9];
    const float* Wr     = (const float*)d_in[10];
    const float* br     = (const float*)d_in[11];
    const float* W_out  = (const float*)d_in[12];
    float* out = (float*)d_out;

    float* ws = (float*)d_ws;
    size_t off = 0;
    float* x_act  = ws + off; off += (size_t)B * S * DI;
    float* Bmb    = ws + off; off += (size_t)B * S * N;
    float* Cmb    = ws + off; off += (size_t)B * S * N;
    float* rdegp  = ws + off; off += (size_t)B * S;
    int*   flagI  = (int*)(ws + off); off += S;
    float* Ebuf   = ws + off; off += (size_t)B * S * DI;
    float* zsbuf  = ws + off; off += (size_t)B * S * DI;
    float* hlast  = ws + off; off += (size_t)B * DN;
    ushort16* xnb    = (ushort16*)(ws + off); off += (size_t)B * S * D / 2;
    ushort16* yzb    = (ushort16*)(ws + off); off += (size_t)B * S * DI / 2;
    ushort16* histT  = (ushort16*)(ws + off); off += (size_t)B * DN * S / 2;
    ushort16* Gall   = (ushort16*)(ws + off); off += (size_t)2 * NSLOT * B * DN * 32 / 2;
    ushort16* xpb    = (ushort16*)(ws + off); off += (size_t)B * (S + 3) * DI / 2;

    hipMemsetAsync(flagI, 0, S * sizeof(int), stream);
    hipMemsetAsync(xpb, 0, (size_t)B * (S + 3) * DI * 2, stream);

    ln_k<<<B * S, 64, 0, stream>>>(x, ln_w, ln_b, xnb);
    gemmb_k<1><<<dim3(2 * DI / 64, B * S / 64), 256, 0, stream>>>(
        xnb, W_in, nullptr, nullptr, xpb, zsbuf, B * S, 2 * DI, D);
    convm_k<<<dim3(DI / 32, B * S / 32), 256, 0, stream>>>(xpb, conv_w, conv_b, x_act);
    ssmE_k<<<B * S / 4, 256, 0, stream>>>(x_act, W_xp, W_dt, b_dt, Bmb, Cmb, Ebuf);
    deg_k<<<B * S, 64, 0, stream>>>(adj, rdegp, flagI);

    for (int lc = 0; lc < NL; ++lc)
        chunk2_k<<<640, 256, 0, stream>>>(adj, x_act, Ebuf, Bmb, rdegp, flagI,
                                          Wr, br, Gall, histT, hlast, lc);

    y_k<<<B * DI, 256, 0, stream>>>(histT, Cmb, zsbuf, yzb);

    gemmb_k<0><<<dim3(D / 64, B * S / 64), 256, 0, stream>>>(
        yzb, W_out, x, out, nullptr, nullptr, B * S, D, DI);
}